// Round 9
// baseline (209.482 us; speedup 1.0000x reference)
//
#include <hip/hip_runtime.h>
#include <hip/hip_bf16.h>

// Problem dims (fixed)
#define T_DIM 256
#define B_DIM 256
#define F_DIM 128
#define H1_DIM 256
#define H_DIM 128
#define Q_DIM 4
#define TAGS 32
#define TB (T_DIM * B_DIM)   // 65536 rows

typedef __attribute__((ext_vector_type(8))) short bf16x8;
typedef __attribute__((ext_vector_type(4))) float f32x4;

__device__ __forceinline__ float rcpf(float x) { return __builtin_amdgcn_rcpf(x); }

// Clamped Pade(7,6) tanh: 1 trans (rcp) instead of exp+rcp. |err| <= 6.7e-4.
__device__ __forceinline__ float tanh_pade(float x) {
    float xc = __builtin_fminf(__builtin_fmaxf(x, -4.0f), 4.0f);
    float x2 = xc * xc;
    float p = fmaf(x2, fmaf(x2, fmaf(x2, 1.0f, 378.0f), 17325.0f), 135135.0f);
    float q = fmaf(x2, fmaf(x2, fmaf(x2, 28.0f, 3150.0f), 62370.0f), 135135.0f);
    return xc * p * rcpf(q);
}
__device__ __forceinline__ float sig_pade(float x) {
    float t = tanh_pade(0.5f * x);
    return fmaf(0.5f, t, 0.5f);
}

__device__ __forceinline__ unsigned short f2bf(float f) {
    __hip_bfloat16 h = __float2bfloat16(f);   // RNE
    return *reinterpret_cast<unsigned short*>(&h);
}

// DPP cross-lane add within quad: CTRL=0xB1 -> lane^1, CTRL=0x4E -> lane^2
template<int CTRL>
__device__ __forceinline__ float dpp_xadd(float x) {
    int t = __builtin_amdgcn_update_dpp(0, __float_as_int(x), CTRL, 0xF, 0xF, true);
    return x + __int_as_float(t);
}

// ---------------------------------------------------------------------------
// Kernel 0: weight prep into MFMA B-fragment order (bf16).
// Wp[((kk*NB + nb)*64 + lane)*8 + e] = W[kk*32 + (lane>>4)*8 + e][nb*16 + (lane&15)]
// ---------------------------------------------------------------------------
__global__ __launch_bounds__(256) void prep_kernel(
    const float* __restrict__ W1, const float* __restrict__ W2,
    const float* __restrict__ Win, const float* __restrict__ Wtag,
    unsigned short* __restrict__ W1p, unsigned short* __restrict__ W2p,
    unsigned short* __restrict__ Winxp, unsigned short* __restrict__ Wtagp)
{
    const int gid0 = blockIdx.x * 256 + threadIdx.x;
    const int gstride = gridDim.x * 256;
    // W1p: K=128 (kk 0..3), N=256 (nb 0..15)
    for (int idx = gid0; idx < 32768; idx += gstride) {
        int e = idx & 7, l = (idx >> 3) & 63, t2 = idx >> 9;
        int nb = t2 & 15, kk = t2 >> 4;
        int k = kk * 32 + (l >> 4) * 8 + e, n = nb * 16 + (l & 15);
        W1p[idx] = f2bf(W1[k * 256 + n]);
    }
    // W2p: K=256 (kk 0..7), N=128 (nb 0..7)
    for (int idx = gid0; idx < 32768; idx += gstride) {
        int e = idx & 7, l = (idx >> 3) & 63, t2 = idx >> 9;
        int nb = t2 & 7, kk = t2 >> 3;
        int k = kk * 32 + (l >> 4) * 8 + e, n = nb * 16 + (l & 15);
        W2p[idx] = f2bf(W2[k * 128 + n]);
    }
    // Winxp: K=128 (kk 0..3), N=16. Winx[k][o] = Win[g][k][q], o=g*4+q
    for (int idx = gid0; idx < 2048; idx += gstride) {
        int e = idx & 7, l = (idx >> 3) & 63, kk = idx >> 9;
        int k = kk * 32 + (l >> 4) * 8 + e, o = l & 15;
        Winxp[idx] = f2bf(Win[(o >> 2) * 1024 + k * 4 + (o & 3)]);
    }
    // Wtagp: K=128 (kk 0..3), N=32 (nt 0..1)
    for (int idx = gid0; idx < 4096; idx += gstride) {
        int e = idx & 7, l = (idx >> 3) & 63, t2 = idx >> 9;
        int nt = t2 & 1, kk = t2 >> 1;
        int k = kk * 32 + (l >> 4) * 8 + e, n = nt * 16 + (l & 15);
        Wtagp[idx] = f2bf(Wtag[k * 32 + n]);
    }
}

// ---------------------------------------------------------------------------
// Kernel 1: MFMA MLP + fused Win_x projection.
// NSP[row,o] = tanh(tanh(X@W1+b1)@W2+b2) @ Winx[:,o]
// ---------------------------------------------------------------------------
__global__ __launch_bounds__(256) void mlp_mfma_kernel(
    const float* __restrict__ X, const unsigned short* __restrict__ W1p,
    const float* __restrict__ b1, const unsigned short* __restrict__ W2p,
    const float* __restrict__ b2, const unsigned short* __restrict__ Winxp,
    float* __restrict__ NSP)
{
    __shared__ __align__(16) unsigned short a1_s[64 * 256];   // 32 KB, stride 512 B
    __shared__ __align__(16) unsigned short xns_s[64 * 128];  // 16 KB: X, then ns

    const int tid = threadIdx.x;
    const int w = tid >> 6;
    const int lane = tid & 63;
    const int lr = lane & 15;
    const int lg = lane >> 4;
    const long rowbase = (long)blockIdx.x * 64;

    char* const a1c = (char*)a1_s;
    char* const xnc = (char*)xns_s;

    // ---- stage X tile (64x128 f32 -> bf16, swizzled) ----
    {
        const int r = tid >> 2;
        const int qc = tid & 3;
        const float4* xg = (const float4*)(X + (rowbase + r) * 128 + qc * 32);
#pragma unroll
        for (int i = 0; i < 4; i++) {
            float4 lo = xg[i * 2], hi = xg[i * 2 + 1];
            bf16x8 v;
            v[0] = (short)f2bf(lo.x); v[1] = (short)f2bf(lo.y);
            v[2] = (short)f2bf(lo.z); v[3] = (short)f2bf(lo.w);
            v[4] = (short)f2bf(hi.x); v[5] = (short)f2bf(hi.y);
            v[6] = (short)f2bf(hi.z); v[7] = (short)f2bf(hi.w);
            int byte = (r * 256 + qc * 64 + i * 16) ^ ((r & 7) << 4);
            *(bf16x8*)(xnc + byte) = v;
        }
    }
    __syncthreads();

    // ---- Phase A: a1 = tanh(X @ W1 + b1), wave w -> cols w*64..+63 ----
    {
        f32x4 acc[4][4];
#pragma unroll
        for (int mi = 0; mi < 4; mi++)
#pragma unroll
            for (int j = 0; j < 4; j++) acc[mi][j] = (f32x4){0.f, 0.f, 0.f, 0.f};

        const bf16x8* w1v = (const bf16x8*)W1p;
#pragma unroll
        for (int kk = 0; kk < 4; kk++) {
            bf16x8 af[4];
#pragma unroll
            for (int mi = 0; mi < 4; mi++) {
                int row = mi * 16 + lr;
                int byte = (row * 256 + kk * 64 + lg * 16) ^ ((row & 7) << 4);
                af[mi] = *(const bf16x8*)(xnc + byte);
            }
            bf16x8 bfv[4];
#pragma unroll
            for (int j = 0; j < 4; j++)
                bfv[j] = w1v[(kk * 16 + (w * 4 + j)) * 64 + lane];
#pragma unroll
            for (int mi = 0; mi < 4; mi++)
#pragma unroll
                for (int j = 0; j < 4; j++)
                    acc[mi][j] = __builtin_amdgcn_mfma_f32_16x16x32_bf16(
                        af[mi], bfv[j], acc[mi][j], 0, 0, 0);
        }

        float b1v[4];
#pragma unroll
        for (int j = 0; j < 4; j++) b1v[j] = b1[(w * 4 + j) * 16 + lr];
#pragma unroll
        for (int mi = 0; mi < 4; mi++)
#pragma unroll
            for (int j = 0; j < 4; j++)
#pragma unroll
                for (int reg = 0; reg < 4; reg++) {
                    int row = mi * 16 + lg * 4 + reg;
                    int col = (w * 4 + j) * 16 + lr;
                    float v = tanh_pade(acc[mi][j][reg] + b1v[j]);
                    int byte = (row * 512 + col * 2) ^ ((row & 7) << 4);
                    *(unsigned short*)(a1c + byte) = f2bf(v);
                }
    }
    __syncthreads();

    // ---- Phase B: ns = tanh(a1 @ W2 + b2), wave w -> cols w*32..+31 ----
    {
        f32x4 acc[4][2];
#pragma unroll
        for (int mi = 0; mi < 4; mi++)
#pragma unroll
            for (int j = 0; j < 2; j++) acc[mi][j] = (f32x4){0.f, 0.f, 0.f, 0.f};

        const bf16x8* w2v = (const bf16x8*)W2p;
#pragma unroll
        for (int kk = 0; kk < 8; kk++) {
            bf16x8 af[4];
#pragma unroll
            for (int mi = 0; mi < 4; mi++) {
                int row = mi * 16 + lr;
                int byte = (row * 512 + kk * 64 + lg * 16) ^ ((row & 7) << 4);
                af[mi] = *(const bf16x8*)(a1c + byte);
            }
            bf16x8 bfv[2];
#pragma unroll
            for (int j = 0; j < 2; j++)
                bfv[j] = w2v[(kk * 8 + (w * 2 + j)) * 64 + lane];
#pragma unroll
            for (int mi = 0; mi < 4; mi++)
#pragma unroll
                for (int j = 0; j < 2; j++)
                    acc[mi][j] = __builtin_amdgcn_mfma_f32_16x16x32_bf16(
                        af[mi], bfv[j], acc[mi][j], 0, 0, 0);
        }

        float b2v[2];
#pragma unroll
        for (int j = 0; j < 2; j++) b2v[j] = b2[(w * 2 + j) * 16 + lr];
#pragma unroll
        for (int mi = 0; mi < 4; mi++)
#pragma unroll
            for (int j = 0; j < 2; j++)
#pragma unroll
                for (int reg = 0; reg < 4; reg++) {
                    int row = mi * 16 + lg * 4 + reg;
                    int col = (w * 2 + j) * 16 + lr;
                    float v = tanh_pade(acc[mi][j][reg] + b2v[j]);
                    int byte = (row * 256 + col * 2) ^ ((row & 7) << 4);
                    *(unsigned short*)(xnc + byte) = f2bf(v);
                }
    }
    __syncthreads();

    // ---- NSP: nsp = ns @ Winx   (wave w -> rows w*16..+15) ----
    {
        f32x4 acc = (f32x4){0.f, 0.f, 0.f, 0.f};
        const bf16x8* wxv = (const bf16x8*)Winxp;
#pragma unroll
        for (int kk = 0; kk < 4; kk++) {
            int row = w * 16 + lr;
            int byte = (row * 256 + kk * 64 + lg * 16) ^ ((row & 7) << 4);
            bf16x8 af = *(const bf16x8*)(xnc + byte);
            bf16x8 bfv = wxv[kk * 64 + lane];
            acc = __builtin_amdgcn_mfma_f32_16x16x32_bf16(af, bfv, acc, 0, 0, 0);
        }
#pragma unroll
        for (int reg = 0; reg < 4; reg++) {
            int row = w * 16 + lg * 4 + reg;
            NSP[(rowbase + row) * 16 + lr] = acc[reg];
        }
    }
}

// ---------------------------------------------------------------------------
// Kernel 2: adj transpose. adjT[j][i] = adj[i][j]
// ---------------------------------------------------------------------------
__global__ __launch_bounds__(256) void transpose_kernel(
    const float* __restrict__ adj, float* __restrict__ adjT)
{
    __shared__ float tile[32][33];
    const int tid = threadIdx.x;
    const int bx = blockIdx.x & 7, by = blockIdx.x >> 3;
    const int lx = tid & 31, ly = (tid >> 5) * 4;
#pragma unroll
    for (int r = 0; r < 4; r++)
        tile[ly + r][lx] = adj[(long)(by * 32 + ly + r) * 256 + bx * 32 + lx];
    __syncthreads();
#pragma unroll
    for (int r = 0; r < 4; r++)
        adjT[(long)(bx * 32 + ly + r) * 256 + by * 32 + lx] = tile[lx][ly + r];
}

// ---------------------------------------------------------------------------
// Kernel 3: AX[t,i,o] = b_in[o] + sum_j adj[i,j] * NSP[t,j,o]
// ---------------------------------------------------------------------------
__global__ __launch_bounds__(256) void aggx_kernel(
    const float* __restrict__ adjT, const float* __restrict__ NSP,
    const float* __restrict__ b_in, float* __restrict__ AX)
{
    __shared__ float4 nsp_s[256 * 4];
    const int tid = threadIdx.x;
    const int t = blockIdx.x;
    {
        const float4* g = (const float4*)(NSP + (long)t * 4096);
#pragma unroll
        for (int i = 0; i < 4; i++) nsp_s[tid + i * 256] = g[tid + i * 256];
    }
    __syncthreads();

    float4 acc[4];
#pragma unroll
    for (int p = 0; p < 4; p++) acc[p] = ((const float4*)b_in)[p];

    const float* arow = adjT + tid;
    float a[8], an[8];
#pragma unroll
    for (int m = 0; m < 8; m++) an[m] = arow[m * 256];
    for (int j0 = 0; j0 < 256; j0 += 8) {
#pragma unroll
        for (int m = 0; m < 8; m++) a[m] = an[m];
        if (j0 + 8 < 256) {
#pragma unroll
            for (int m = 0; m < 8; m++) an[m] = arow[(j0 + 8 + m) * 256];
        }
#pragma unroll
        for (int m = 0; m < 8; m++) {
            float av = a[m];
#pragma unroll
            for (int p = 0; p < 4; p++) {
                float4 nv = nsp_s[(j0 + m) * 4 + p];
                acc[p].x += av * nv.x; acc[p].y += av * nv.y;
                acc[p].z += av * nv.z; acc[p].w += av * nv.w;
            }
        }
    }
    float4* out = (float4*)(AX + (long)t * 4096 + tid * 16);
#pragma unroll
    for (int p = 0; p < 4; p++) out[p] = acc[p];
}

// ---------------------------------------------------------------------------
// Kernel 4: LSTM scan + FUSED tag head. One wave per batch element.
// Round-9: Pade activations (1 rcp vs exp+rcp -> halves trans-pipe pressure),
// h2-split with early ds_write of the low half.
// ---------------------------------------------------------------------------
__device__ __forceinline__ int hhoff(int row, int inrow) {
    return (row * 512 + inrow) ^ ((row & 7) << 4);
}

__global__ __attribute__((amdgpu_waves_per_eu(1, 1))) __launch_bounds__(64)
void lstm_head_kernel(
    const float* __restrict__ AX, const float* __restrict__ Win,
    const float* __restrict__ Wout, const float* __restrict__ b_out,
    const unsigned short* __restrict__ Wtagp, const float* __restrict__ btag,
    float* __restrict__ OUT)
{
    __shared__ __align__(16) float hh[T_DIM * 128];   // 128 KB, swizzled rows
    char* const hhc = (char*)hh;

    const int lane = threadIdx.x;
    const int b = blockIdx.x;
    const int o = lane >> 2;
    const int s = lane & 3;
    const int g_o = o >> 2, q_o = o & 3;

    // wh[m*4+j] = Win_h[k][o], k = m*16 + s*4 + j
    float wh[32];
#pragma unroll
    for (int m = 0; m < 8; m++)
#pragma unroll
        for (int j = 0; j < 4; j++)
            wh[m * 4 + j] = Win[g_o * 1024 + 512 + (m * 16 + s * 4 + j) * 4 + q_o];

    float wo[4][4][2];
    float bo[4][2];
#pragma unroll
    for (int g = 0; g < 4; g++) {
#pragma unroll
        for (int h2 = 0; h2 < 2; h2++) bo[g][h2] = b_out[g * 128 + lane + 64 * h2];
#pragma unroll
        for (int q = 0; q < 4; q++)
#pragma unroll
            for (int h2 = 0; h2 < 2; h2++)
                wo[g][q][h2] = Wout[(g * 4 + q) * 128 + lane + 64 * h2];
    }

    float c0 = 0.f, c1 = 0.f;
    *(float*)(hhc + hhoff(255, lane * 4)) = 0.f;
    *(float*)(hhc + hhoff(255, 256 + lane * 4)) = 0.f;

    // distance-2 AX prefetch, pointer-bump addressing
    const float* axp = AX + (long)b * 16 + o;
    float ax_cur = axp[0];
    float ax_nxt = axp[B_DIM * 16];
    axp += 2 * B_DIM * 16;

    for (int t = 0; t < T_DIM; t++) {
        const int rp = (t + 255) & 255;
        float a0 = 0.f, a1 = 0.f, a2 = 0.f, a3 = 0.f;
#pragma unroll
        for (int half = 0; half < 2; half++) {
            float4 hv[4];
#pragma unroll
            for (int m = 0; m < 4; m++)
                hv[m] = *(const float4*)(hhc + hhoff(rp, (half * 4 + m) * 64 + s * 16));
            const float* w = wh + half * 16;
            a0 += hv[0].x*w[0]  + hv[0].y*w[1]  + hv[0].z*w[2]  + hv[0].w*w[3];
            a1 += hv[1].x*w[4]  + hv[1].y*w[5]  + hv[1].z*w[6]  + hv[1].w*w[7];
            a2 += hv[2].x*w[8]  + hv[2].y*w[9]  + hv[2].z*w[10] + hv[2].w*w[11];
            a3 += hv[3].x*w[12] + hv[3].y*w[13] + hv[3].z*w[14] + hv[3].w*w[15];
        }
        float acc = (a0 + a1) + (a2 + a3);
        acc = dpp_xadd<0xB1>(acc);
        acc = dpp_xadd<0x4E>(acc);
        float zv = tanh_pade(acc + ax_cur);

        // rotate distance-2 prefetch (clamped pointer bump)
        ax_cur = ax_nxt;
        ax_nxt = *axp;
        if (t < T_DIM - 3) axp += B_DIM * 16;

        unsigned zb = __float_as_uint(zv);
        float z[16];
#pragma unroll
        for (int oo = 0; oo < 16; oo++)
            z[oo] = __uint_as_float(__builtin_amdgcn_readlane(zb, oo * 4));

        // ---- half 0: compute + EARLY write ----
        {
            float gp_f = bo[0][0] + z[0]*wo[0][0][0] + z[1]*wo[0][1][0] + z[2]*wo[0][2][0] + z[3]*wo[0][3][0];
            float gp_i = bo[1][0] + z[4]*wo[1][0][0] + z[5]*wo[1][1][0] + z[6]*wo[1][2][0] + z[7]*wo[1][3][0];
            float gp_g = bo[2][0] + z[8]*wo[2][0][0] + z[9]*wo[2][1][0] + z[10]*wo[2][2][0] + z[11]*wo[2][3][0];
            float gp_o = bo[3][0] + z[12]*wo[3][0][0] + z[13]*wo[3][1][0] + z[14]*wo[3][2][0] + z[15]*wo[3][3][0];
            float fg = sig_pade(gp_f);
            float ig = sig_pade(gp_i);
            float gg = tanh_pade(gp_g);
            float og = sig_pade(gp_o);
            c0 = fg * c0 + ig * gg;
            float h0 = og * tanh_pade(c0);
            *(float*)(hhc + hhoff(t, lane * 4)) = h0;
        }
        __builtin_amdgcn_sched_barrier(0);   // pin: w0 issues before half-1 math
        // ---- half 1 ----
        {
            float gp_f = bo[0][1] + z[0]*wo[0][0][1] + z[1]*wo[0][1][1] + z[2]*wo[0][2][1] + z[3]*wo[0][3][1];
            float gp_i = bo[1][1] + z[4]*wo[1][0][1] + z[5]*wo[1][1][1] + z[6]*wo[1][2][1] + z[7]*wo[1][3][1];
            float gp_g = bo[2][1] + z[8]*wo[2][0][1] + z[9]*wo[2][1][1] + z[10]*wo[2][2][1] + z[11]*wo[2][3][1];
            float gp_o = bo[3][1] + z[12]*wo[3][0][1] + z[13]*wo[3][1][1] + z[14]*wo[3][2][1] + z[15]*wo[3][3][1];
            float fg = sig_pade(gp_f);
            float ig = sig_pade(gp_i);
            float gg = tanh_pade(gp_g);
            float og = sig_pade(gp_o);
            c1 = fg * c1 + ig * gg;
            float h1 = og * tanh_pade(c1);
            *(float*)(hhc + hhoff(t, 256 + lane * 4)) = h1;
        }
    }

    // ================= fused tag head =================
    // logits[256t x 32tag] = hh @ Wtag + btag ; out = log_softmax(rows)
    const int lr = lane & 15;
    const int lg = lane >> 4;
    const bf16x8* wtv = (const bf16x8*)Wtagp;
    bf16x8 wt[4][2];
#pragma unroll
    for (int kk = 0; kk < 4; kk++)
#pragma unroll
        for (int nt = 0; nt < 2; nt++)
            wt[kk][nt] = wtv[(kk * 2 + nt) * 64 + lane];
    float bt0 = btag[lr], bt1 = btag[16 + lr];

    for (int mi = 0; mi < 16; mi++) {
        f32x4 acc0 = (f32x4){0.f, 0.f, 0.f, 0.f};
        f32x4 acc1 = (f32x4){0.f, 0.f, 0.f, 0.f};
        const int arow = mi * 16 + lr;
#pragma unroll
        for (int kk = 0; kk < 4; kk++) {
            float4 lo = *(const float4*)(hhc + hhoff(arow, kk * 128 + lg * 32));
            float4 hi = *(const float4*)(hhc + hhoff(arow, kk * 128 + lg * 32 + 16));
            bf16x8 af;
            af[0] = (short)f2bf(lo.x); af[1] = (short)f2bf(lo.y);
            af[2] = (short)f2bf(lo.z); af[3] = (short)f2bf(lo.w);
            af[4] = (short)f2bf(hi.x); af[5] = (short)f2bf(hi.y);
            af[6] = (short)f2bf(hi.z); af[7] = (short)f2bf(hi.w);
            acc0 = __builtin_amdgcn_mfma_f32_16x16x32_bf16(af, wt[kk][0], acc0, 0, 0, 0);
            acc1 = __builtin_amdgcn_mfma_f32_16x16x32_bf16(af, wt[kk][1], acc1, 0, 0, 0);
        }
        // per-row (over 32 tags) log_softmax. Row r = mi*16 + lg*4 + reg is
        // held by the 16 lanes of group lg (cols = lane&15).
        float s0[4], s1[4], mx[4], se[4];
#pragma unroll
        for (int reg = 0; reg < 4; reg++) {
            s0[reg] = acc0[reg] + bt0;
            s1[reg] = acc1[reg] + bt1;
            float m = fmaxf(s0[reg], s1[reg]);
#pragma unroll
            for (int d = 8; d >= 1; d >>= 1) m = fmaxf(m, __shfl_xor(m, d));
            mx[reg] = m;
            float e = __expf(s0[reg] - m) + __expf(s1[reg] - m);
#pragma unroll
            for (int d = 8; d >= 1; d >>= 1) e += __shfl_xor(e, d);
            se[reg] = __logf(e);
        }
#pragma unroll
        for (int reg = 0; reg < 4; reg++) {
            long t = mi * 16 + lg * 4 + reg;
            long base = (t * B_DIM + b) * 32;
            OUT[base + lr]      = s0[reg] - mx[reg] - se[reg];
            OUT[base + 16 + lr] = s1[reg] - mx[reg] - se[reg];
        }
    }
}

// ---------------------------------------------------------------------------
extern "C" void kernel_launch(void* const* d_in, const int* in_sizes, int n_in,
                              void* d_out, int out_size, void* d_ws, size_t ws_size,
                              hipStream_t stream)
{
    const float* X    = (const float*)d_in[0];   // [T,B,F]
    const float* adj  = (const float*)d_in[1];   // [B,B]
    const float* W1   = (const float*)d_in[2];   // [F,H1]
    const float* b1   = (const float*)d_in[3];
    const float* W2   = (const float*)d_in[4];   // [H1,H]
    const float* b2   = (const float*)d_in[5];
    const float* Win  = (const float*)d_in[6];   // [4,F+H,Q]
    const float* b_in = (const float*)d_in[7];   // [4,Q]
    const float* Wout = (const float*)d_in[8];   // [4,Q,H]
    const float* bout = (const float*)d_in[9];   // [4,H]
    const float* Wtag = (const float*)d_in[10];  // [H,TAGS]
    const float* btag = (const float*)d_in[11];
    float* OUT = (float*)d_out;

    float* ws = (float*)d_ws;
    float* NSP  = ws;                    // [T,B,16]  1,048,576 f
    float* adjT = ws + 1048576;          // [B,B]        65,536 f
    float* AX   = ws + 1114112;          // [T,B,16]  1,048,576 f
    unsigned short* W1p   = (unsigned short*)(ws + 2162688);   // 32768 bf16
    unsigned short* W2p   = W1p + 32768;                       // 32768 bf16
    unsigned short* Winxp = W2p + 32768;                       //  2048 bf16
    unsigned short* Wtagp = Winxp + 2048;                      //  4096 bf16

    prep_kernel<<<dim3(64), dim3(256), 0, stream>>>(W1, W2, Win, Wtag, W1p, W2p, Winxp, Wtagp);
    mlp_mfma_kernel<<<dim3(TB / 64), dim3(256), 0, stream>>>(X, W1p, b1, W2p, b2, Winxp, NSP);
    transpose_kernel<<<dim3(64), dim3(256), 0, stream>>>(adj, adjT);
    aggx_kernel<<<dim3(256), dim3(256), 0, stream>>>(adjT, NSP, b_in, AX);
    lstm_head_kernel<<<dim3(B_DIM), dim3(64), 0, stream>>>(AX, Win, Wout, bout, Wtagp, btag, OUT);
}

// Round 10
// 178.290 us; speedup vs baseline: 1.1750x; 1.1750x over previous
//
#include <hip/hip_runtime.h>
#include <hip/hip_bf16.h>

// Problem dims (fixed)
#define T_DIM 256
#define B_DIM 256
#define F_DIM 128
#define H1_DIM 256
#define H_DIM 128
#define Q_DIM 4
#define TAGS 32
#define TB (T_DIM * B_DIM)   // 65536 rows

typedef __attribute__((ext_vector_type(8))) short bf16x8;
typedef __attribute__((ext_vector_type(4))) float f32x4;

__device__ __forceinline__ float rcpf(float x) { return __builtin_amdgcn_rcpf(x); }
__device__ __forceinline__ float exp2f_hw(float x) { return __builtin_amdgcn_exp2f(x); }

// v_exp_f32 IS exp2: fold the 2x / -x scaling into the log2e constant.
// (Round-8 form — round-9's Pade variant lengthened the dependent chain and
// regressed 24 us; reverted.)
__device__ __forceinline__ float tanhf_fast(float x) {
    float e = exp2f_hw(2.885390081777927f * x);   // exp(2x)
    return 1.0f - 2.0f * rcpf(e + 1.0f);
}
__device__ __forceinline__ float sigf(float x) {
    return rcpf(1.0f + exp2f_hw(-1.4426950408889634f * x));
}

__device__ __forceinline__ unsigned short f2bf(float f) {
    __hip_bfloat16 h = __float2bfloat16(f);   // RNE
    return *reinterpret_cast<unsigned short*>(&h);
}

// DPP cross-lane add within quad: CTRL=0xB1 -> lane^1, CTRL=0x4E -> lane^2
template<int CTRL>
__device__ __forceinline__ float dpp_xadd(float x) {
    int t = __builtin_amdgcn_update_dpp(0, __float_as_int(x), CTRL, 0xF, 0xF, true);
    return x + __int_as_float(t);
}

// ---------------------------------------------------------------------------
// Kernel 0: weight prep into MFMA B-fragment order (bf16).
// Wp[((kk*NB + nb)*64 + lane)*8 + e] = W[kk*32 + (lane>>4)*8 + e][nb*16 + (lane&15)]
// ---------------------------------------------------------------------------
__global__ __launch_bounds__(256) void prep_kernel(
    const float* __restrict__ W1, const float* __restrict__ W2,
    const float* __restrict__ Win, const float* __restrict__ Wtag,
    unsigned short* __restrict__ W1p, unsigned short* __restrict__ W2p,
    unsigned short* __restrict__ Winxp, unsigned short* __restrict__ Wtagp)
{
    const int gid0 = blockIdx.x * 256 + threadIdx.x;
    const int gstride = gridDim.x * 256;
    // W1p: K=128 (kk 0..3), N=256 (nb 0..15)
    for (int idx = gid0; idx < 32768; idx += gstride) {
        int e = idx & 7, l = (idx >> 3) & 63, t2 = idx >> 9;
        int nb = t2 & 15, kk = t2 >> 4;
        int k = kk * 32 + (l >> 4) * 8 + e, n = nb * 16 + (l & 15);
        W1p[idx] = f2bf(W1[k * 256 + n]);
    }
    // W2p: K=256 (kk 0..7), N=128 (nb 0..7)
    for (int idx = gid0; idx < 32768; idx += gstride) {
        int e = idx & 7, l = (idx >> 3) & 63, t2 = idx >> 9;
        int nb = t2 & 7, kk = t2 >> 3;
        int k = kk * 32 + (l >> 4) * 8 + e, n = nb * 16 + (l & 15);
        W2p[idx] = f2bf(W2[k * 128 + n]);
    }
    // Winxp: K=128 (kk 0..3), N=16. Winx[k][o] = Win[g][k][q], o=g*4+q
    for (int idx = gid0; idx < 2048; idx += gstride) {
        int e = idx & 7, l = (idx >> 3) & 63, kk = idx >> 9;
        int k = kk * 32 + (l >> 4) * 8 + e, o = l & 15;
        Winxp[idx] = f2bf(Win[(o >> 2) * 1024 + k * 4 + (o & 3)]);
    }
    // Wtagp: K=128 (kk 0..3), N=32 (nt 0..1)
    for (int idx = gid0; idx < 4096; idx += gstride) {
        int e = idx & 7, l = (idx >> 3) & 63, t2 = idx >> 9;
        int nt = t2 & 1, kk = t2 >> 1;
        int k = kk * 32 + (l >> 4) * 8 + e, n = nt * 16 + (l & 15);
        Wtagp[idx] = f2bf(Wtag[k * 32 + n]);
    }
}

// ---------------------------------------------------------------------------
// Kernel 1: MFMA MLP + fused Win_x projection.
// NSP[row,o] = tanh(tanh(X@W1+b1)@W2+b2) @ Winx[:,o]
// ---------------------------------------------------------------------------
__global__ __launch_bounds__(256) void mlp_mfma_kernel(
    const float* __restrict__ X, const unsigned short* __restrict__ W1p,
    const float* __restrict__ b1, const unsigned short* __restrict__ W2p,
    const float* __restrict__ b2, const unsigned short* __restrict__ Winxp,
    float* __restrict__ NSP)
{
    __shared__ __align__(16) unsigned short a1_s[64 * 256];   // 32 KB, stride 512 B
    __shared__ __align__(16) unsigned short xns_s[64 * 128];  // 16 KB: X, then ns

    const int tid = threadIdx.x;
    const int w = tid >> 6;
    const int lane = tid & 63;
    const int lr = lane & 15;
    const int lg = lane >> 4;
    const long rowbase = (long)blockIdx.x * 64;

    char* const a1c = (char*)a1_s;
    char* const xnc = (char*)xns_s;

    // ---- stage X tile (64x128 f32 -> bf16, swizzled) ----
    {
        const int r = tid >> 2;
        const int qc = tid & 3;
        const float4* xg = (const float4*)(X + (rowbase + r) * 128 + qc * 32);
#pragma unroll
        for (int i = 0; i < 4; i++) {
            float4 lo = xg[i * 2], hi = xg[i * 2 + 1];
            bf16x8 v;
            v[0] = (short)f2bf(lo.x); v[1] = (short)f2bf(lo.y);
            v[2] = (short)f2bf(lo.z); v[3] = (short)f2bf(lo.w);
            v[4] = (short)f2bf(hi.x); v[5] = (short)f2bf(hi.y);
            v[6] = (short)f2bf(hi.z); v[7] = (short)f2bf(hi.w);
            int byte = (r * 256 + qc * 64 + i * 16) ^ ((r & 7) << 4);
            *(bf16x8*)(xnc + byte) = v;
        }
    }
    __syncthreads();

    // ---- Phase A: a1 = tanh(X @ W1 + b1), wave w -> cols w*64..+63 ----
    {
        f32x4 acc[4][4];
#pragma unroll
        for (int mi = 0; mi < 4; mi++)
#pragma unroll
            for (int j = 0; j < 4; j++) acc[mi][j] = (f32x4){0.f, 0.f, 0.f, 0.f};

        const bf16x8* w1v = (const bf16x8*)W1p;
#pragma unroll
        for (int kk = 0; kk < 4; kk++) {
            bf16x8 af[4];
#pragma unroll
            for (int mi = 0; mi < 4; mi++) {
                int row = mi * 16 + lr;
                int byte = (row * 256 + kk * 64 + lg * 16) ^ ((row & 7) << 4);
                af[mi] = *(const bf16x8*)(xnc + byte);
            }
            bf16x8 bfv[4];
#pragma unroll
            for (int j = 0; j < 4; j++)
                bfv[j] = w1v[(kk * 16 + (w * 4 + j)) * 64 + lane];
#pragma unroll
            for (int mi = 0; mi < 4; mi++)
#pragma unroll
                for (int j = 0; j < 4; j++)
                    acc[mi][j] = __builtin_amdgcn_mfma_f32_16x16x32_bf16(
                        af[mi], bfv[j], acc[mi][j], 0, 0, 0);
        }

        float b1v[4];
#pragma unroll
        for (int j = 0; j < 4; j++) b1v[j] = b1[(w * 4 + j) * 16 + lr];
#pragma unroll
        for (int mi = 0; mi < 4; mi++)
#pragma unroll
            for (int j = 0; j < 4; j++)
#pragma unroll
                for (int reg = 0; reg < 4; reg++) {
                    int row = mi * 16 + lg * 4 + reg;
                    int col = (w * 4 + j) * 16 + lr;
                    float v = tanhf_fast(acc[mi][j][reg] + b1v[j]);
                    int byte = (row * 512 + col * 2) ^ ((row & 7) << 4);
                    *(unsigned short*)(a1c + byte) = f2bf(v);
                }
    }
    __syncthreads();

    // ---- Phase B: ns = tanh(a1 @ W2 + b2), wave w -> cols w*32..+31 ----
    {
        f32x4 acc[4][2];
#pragma unroll
        for (int mi = 0; mi < 4; mi++)
#pragma unroll
            for (int j = 0; j < 2; j++) acc[mi][j] = (f32x4){0.f, 0.f, 0.f, 0.f};

        const bf16x8* w2v = (const bf16x8*)W2p;
#pragma unroll
        for (int kk = 0; kk < 8; kk++) {
            bf16x8 af[4];
#pragma unroll
            for (int mi = 0; mi < 4; mi++) {
                int row = mi * 16 + lr;
                int byte = (row * 512 + kk * 64 + lg * 16) ^ ((row & 7) << 4);
                af[mi] = *(const bf16x8*)(a1c + byte);
            }
            bf16x8 bfv[2];
#pragma unroll
            for (int j = 0; j < 2; j++)
                bfv[j] = w2v[(kk * 8 + (w * 2 + j)) * 64 + lane];
#pragma unroll
            for (int mi = 0; mi < 4; mi++)
#pragma unroll
                for (int j = 0; j < 2; j++)
                    acc[mi][j] = __builtin_amdgcn_mfma_f32_16x16x32_bf16(
                        af[mi], bfv[j], acc[mi][j], 0, 0, 0);
        }

        float b2v[2];
#pragma unroll
        for (int j = 0; j < 2; j++) b2v[j] = b2[(w * 2 + j) * 16 + lr];
#pragma unroll
        for (int mi = 0; mi < 4; mi++)
#pragma unroll
            for (int j = 0; j < 2; j++)
#pragma unroll
                for (int reg = 0; reg < 4; reg++) {
                    int row = mi * 16 + lg * 4 + reg;
                    int col = (w * 2 + j) * 16 + lr;
                    float v = tanhf_fast(acc[mi][j][reg] + b2v[j]);
                    int byte = (row * 256 + col * 2) ^ ((row & 7) << 4);
                    *(unsigned short*)(xnc + byte) = f2bf(v);
                }
    }
    __syncthreads();

    // ---- NSP: nsp = ns @ Winx   (wave w -> rows w*16..+15) ----
    {
        f32x4 acc = (f32x4){0.f, 0.f, 0.f, 0.f};
        const bf16x8* wxv = (const bf16x8*)Winxp;
#pragma unroll
        for (int kk = 0; kk < 4; kk++) {
            int row = w * 16 + lr;
            int byte = (row * 256 + kk * 64 + lg * 16) ^ ((row & 7) << 4);
            bf16x8 af = *(const bf16x8*)(xnc + byte);
            bf16x8 bfv = wxv[kk * 64 + lane];
            acc = __builtin_amdgcn_mfma_f32_16x16x32_bf16(af, bfv, acc, 0, 0, 0);
        }
#pragma unroll
        for (int reg = 0; reg < 4; reg++) {
            int row = w * 16 + lg * 4 + reg;
            NSP[(rowbase + row) * 16 + lr] = acc[reg];
        }
    }
}

// ---------------------------------------------------------------------------
// Kernel 2: adj transpose. adjT[j][i] = adj[i][j]
// ---------------------------------------------------------------------------
__global__ __launch_bounds__(256) void transpose_kernel(
    const float* __restrict__ adj, float* __restrict__ adjT)
{
    __shared__ float tile[32][33];
    const int tid = threadIdx.x;
    const int bx = blockIdx.x & 7, by = blockIdx.x >> 3;
    const int lx = tid & 31, ly = (tid >> 5) * 4;
#pragma unroll
    for (int r = 0; r < 4; r++)
        tile[ly + r][lx] = adj[(long)(by * 32 + ly + r) * 256 + bx * 32 + lx];
    __syncthreads();
#pragma unroll
    for (int r = 0; r < 4; r++)
        adjT[(long)(bx * 32 + ly + r) * 256 + by * 32 + lx] = tile[lx][ly + r];
}

// ---------------------------------------------------------------------------
// Kernel 3: AX[t,i,o] = b_in[o] + sum_j adj[i,j] * NSP[t,j,o]
// ---------------------------------------------------------------------------
__global__ __launch_bounds__(256) void aggx_kernel(
    const float* __restrict__ adjT, const float* __restrict__ NSP,
    const float* __restrict__ b_in, float* __restrict__ AX)
{
    __shared__ float4 nsp_s[256 * 4];
    const int tid = threadIdx.x;
    const int t = blockIdx.x;
    {
        const float4* g = (const float4*)(NSP + (long)t * 4096);
#pragma unroll
        for (int i = 0; i < 4; i++) nsp_s[tid + i * 256] = g[tid + i * 256];
    }
    __syncthreads();

    float4 acc[4];
#pragma unroll
    for (int p = 0; p < 4; p++) acc[p] = ((const float4*)b_in)[p];

    const float* arow = adjT + tid;
    float a[8], an[8];
#pragma unroll
    for (int m = 0; m < 8; m++) an[m] = arow[m * 256];
    for (int j0 = 0; j0 < 256; j0 += 8) {
#pragma unroll
        for (int m = 0; m < 8; m++) a[m] = an[m];
        if (j0 + 8 < 256) {
#pragma unroll
            for (int m = 0; m < 8; m++) an[m] = arow[(j0 + 8 + m) * 256];
        }
#pragma unroll
        for (int m = 0; m < 8; m++) {
            float av = a[m];
#pragma unroll
            for (int p = 0; p < 4; p++) {
                float4 nv = nsp_s[(j0 + m) * 4 + p];
                acc[p].x += av * nv.x; acc[p].y += av * nv.y;
                acc[p].z += av * nv.z; acc[p].w += av * nv.w;
            }
        }
    }
    float4* out = (float4*)(AX + (long)t * 4096 + tid * 16);
#pragma unroll
    for (int p = 0; p < 4; p++) out[p] = acc[p];
}

// ---------------------------------------------------------------------------
// Kernel 4: LSTM scan + FUSED tag head. One wave per batch element.
// Round-10: software-pipelined LDS — next step's h reads are issued right
// after each half's h write, so their ~150cy latency hides under the other
// half's gate math instead of sitting exposed at the loop boundary.
// Dot product consumes preloaded hvlo/hvhi registers (8 parallel chains).
// ---------------------------------------------------------------------------
__device__ __forceinline__ int hhoff(int row, int inrow) {
    return (row * 512 + inrow) ^ ((row & 7) << 4);
}

__global__ __attribute__((amdgpu_waves_per_eu(1, 1))) __launch_bounds__(64)
void lstm_head_kernel(
    const float* __restrict__ AX, const float* __restrict__ Win,
    const float* __restrict__ Wout, const float* __restrict__ b_out,
    const unsigned short* __restrict__ Wtagp, const float* __restrict__ btag,
    float* __restrict__ OUT)
{
    __shared__ __align__(16) float hh[T_DIM * 128];   // 128 KB, swizzled rows
    char* const hhc = (char*)hh;

    const int lane = threadIdx.x;
    const int b = blockIdx.x;
    const int o = lane >> 2;
    const int s = lane & 3;
    const int g_o = o >> 2, q_o = o & 3;

    // wh[m*4+j] = Win_h[k][o], k = m*16 + s*4 + j  (m<4: h[0..63], m>=4: h[64..127])
    float wh[32];
#pragma unroll
    for (int m = 0; m < 8; m++)
#pragma unroll
        for (int j = 0; j < 4; j++)
            wh[m * 4 + j] = Win[g_o * 1024 + 512 + (m * 16 + s * 4 + j) * 4 + q_o];

    float wo[4][4][2];
    float bo[4][2];
#pragma unroll
    for (int g = 0; g < 4; g++) {
#pragma unroll
        for (int h2 = 0; h2 < 2; h2++) bo[g][h2] = b_out[g * 128 + lane + 64 * h2];
#pragma unroll
        for (int q = 0; q < 4; q++)
#pragma unroll
            for (int h2 = 0; h2 < 2; h2++)
                wo[g][q][h2] = Wout[(g * 4 + q) * 128 + lane + 64 * h2];
    }

    float c0 = 0.f, c1 = 0.f;
    *(float*)(hhc + hhoff(255, lane * 4)) = 0.f;
    *(float*)(hhc + hhoff(255, 256 + lane * 4)) = 0.f;

    // prologue: preload h(-1) = zeros into the pipeline registers
    float4 hvlo[4], hvhi[4];
#pragma unroll
    for (int m = 0; m < 4; m++)
        hvlo[m] = *(const float4*)(hhc + hhoff(255, m * 64 + s * 16));
#pragma unroll
    for (int m = 0; m < 4; m++)
        hvhi[m] = *(const float4*)(hhc + hhoff(255, 256 + m * 64 + s * 16));

    // distance-2 AX prefetch, pointer-bump addressing
    const float* axp = AX + (long)b * 16 + o;
    float ax_cur = axp[0];
    float ax_nxt = axp[B_DIM * 16];
    axp += 2 * B_DIM * 16;

    for (int t = 0; t < T_DIM; t++) {
        // zpre from preloaded registers: 8 parallel chains, depth 4
        float a0 = hvlo[0].x*wh[0]  + hvlo[0].y*wh[1]  + hvlo[0].z*wh[2]  + hvlo[0].w*wh[3];
        float a1 = hvlo[1].x*wh[4]  + hvlo[1].y*wh[5]  + hvlo[1].z*wh[6]  + hvlo[1].w*wh[7];
        float a2 = hvlo[2].x*wh[8]  + hvlo[2].y*wh[9]  + hvlo[2].z*wh[10] + hvlo[2].w*wh[11];
        float a3 = hvlo[3].x*wh[12] + hvlo[3].y*wh[13] + hvlo[3].z*wh[14] + hvlo[3].w*wh[15];
        float a4 = hvhi[0].x*wh[16] + hvhi[0].y*wh[17] + hvhi[0].z*wh[18] + hvhi[0].w*wh[19];
        float a5 = hvhi[1].x*wh[20] + hvhi[1].y*wh[21] + hvhi[1].z*wh[22] + hvhi[1].w*wh[23];
        float a6 = hvhi[2].x*wh[24] + hvhi[2].y*wh[25] + hvhi[2].z*wh[26] + hvhi[2].w*wh[27];
        float a7 = hvhi[3].x*wh[28] + hvhi[3].y*wh[29] + hvhi[3].z*wh[30] + hvhi[3].w*wh[31];
        float acc = ((a0 + a1) + (a2 + a3)) + ((a4 + a5) + (a6 + a7));
        acc = dpp_xadd<0xB1>(acc);
        acc = dpp_xadd<0x4E>(acc);
        float zv = tanhf_fast(acc + ax_cur);

        // rotate distance-2 prefetch (clamped pointer bump)
        ax_cur = ax_nxt;
        ax_nxt = *axp;
        if (t < T_DIM - 3) axp += B_DIM * 16;

        unsigned zb = __float_as_uint(zv);
        float z[16];
#pragma unroll
        for (int oo = 0; oo < 16; oo++)
            z[oo] = __uint_as_float(__builtin_amdgcn_readlane(zb, oo * 4));

        // ---- half 0: gates -> h0 -> write -> ISSUE next low reads ----
        {
            float gp_f = bo[0][0] + z[0]*wo[0][0][0] + z[1]*wo[0][1][0] + z[2]*wo[0][2][0] + z[3]*wo[0][3][0];
            float gp_i = bo[1][0] + z[4]*wo[1][0][0] + z[5]*wo[1][1][0] + z[6]*wo[1][2][0] + z[7]*wo[1][3][0];
            float gp_g = bo[2][0] + z[8]*wo[2][0][0] + z[9]*wo[2][1][0] + z[10]*wo[2][2][0] + z[11]*wo[2][3][0];
            float gp_o = bo[3][0] + z[12]*wo[3][0][0] + z[13]*wo[3][1][0] + z[14]*wo[3][2][0] + z[15]*wo[3][3][0];
            float fg = sigf(gp_f);
            float ig = sigf(gp_i);
            float gg = tanhf_fast(gp_g);
            float og = sigf(gp_o);
            c0 = fg * c0 + ig * gg;
            float h0 = og * tanhf_fast(c0);
            *(float*)(hhc + hhoff(t, lane * 4)) = h0;
        }
        // early reads of the low half just written (hide latency under half 1)
#pragma unroll
        for (int m = 0; m < 4; m++)
            hvlo[m] = *(const float4*)(hhc + hhoff(t, m * 64 + s * 16));

        // ---- half 1: gates -> h1 -> write -> ISSUE next high reads ----
        {
            float gp_f = bo[0][1] + z[0]*wo[0][0][1] + z[1]*wo[0][1][1] + z[2]*wo[0][2][1] + z[3]*wo[0][3][1];
            float gp_i = bo[1][1] + z[4]*wo[1][0][1] + z[5]*wo[1][1][1] + z[6]*wo[1][2][1] + z[7]*wo[1][3][1];
            float gp_g = bo[2][1] + z[8]*wo[2][0][1] + z[9]*wo[2][1][1] + z[10]*wo[2][2][1] + z[11]*wo[2][3][1];
            float gp_o = bo[3][1] + z[12]*wo[3][0][1] + z[13]*wo[3][1][1] + z[14]*wo[3][2][1] + z[15]*wo[3][3][1];
            float fg = sigf(gp_f);
            float ig = sigf(gp_i);
            float gg = tanhf_fast(gp_g);
            float og = sigf(gp_o);
            c1 = fg * c1 + ig * gg;
            float h1 = og * tanhf_fast(c1);
            *(float*)(hhc + hhoff(t, 256 + lane * 4)) = h1;
        }
#pragma unroll
        for (int m = 0; m < 4; m++)
            hvhi[m] = *(const float4*)(hhc + hhoff(t, 256 + m * 64 + s * 16));
    }

    // ================= fused tag head =================
    // logits[256t x 32tag] = hh @ Wtag + btag ; out = log_softmax(rows)
    const int lr = lane & 15;
    const int lg = lane >> 4;
    const bf16x8* wtv = (const bf16x8*)Wtagp;
    bf16x8 wt[4][2];
#pragma unroll
    for (int kk = 0; kk < 4; kk++)
#pragma unroll
        for (int nt = 0; nt < 2; nt++)
            wt[kk][nt] = wtv[(kk * 2 + nt) * 64 + lane];
    float bt0 = btag[lr], bt1 = btag[16 + lr];

    for (int mi = 0; mi < 16; mi++) {
        f32x4 acc0 = (f32x4){0.f, 0.f, 0.f, 0.f};
        f32x4 acc1 = (f32x4){0.f, 0.f, 0.f, 0.f};
        const int arow = mi * 16 + lr;
#pragma unroll
        for (int kk = 0; kk < 4; kk++) {
            float4 lo = *(const float4*)(hhc + hhoff(arow, kk * 128 + lg * 32));
            float4 hi = *(const float4*)(hhc + hhoff(arow, kk * 128 + lg * 32 + 16));
            bf16x8 af;
            af[0] = (short)f2bf(lo.x); af[1] = (short)f2bf(lo.y);
            af[2] = (short)f2bf(lo.z); af[3] = (short)f2bf(lo.w);
            af[4] = (short)f2bf(hi.x); af[5] = (short)f2bf(hi.y);
            af[6] = (short)f2bf(hi.z); af[7] = (short)f2bf(hi.w);
            acc0 = __builtin_amdgcn_mfma_f32_16x16x32_bf16(af, wt[kk][0], acc0, 0, 0, 0);
            acc1 = __builtin_amdgcn_mfma_f32_16x16x32_bf16(af, wt[kk][1], acc1, 0, 0, 0);
        }
        // per-row (over 32 tags) log_softmax. Row r = mi*16 + lg*4 + reg is
        // held by the 16 lanes of group lg (cols = lane&15).
        float s0[4], s1[4], mx[4], se[4];
#pragma unroll
        for (int reg = 0; reg < 4; reg++) {
            s0[reg] = acc0[reg] + bt0;
            s1[reg] = acc1[reg] + bt1;
            float m = fmaxf(s0[reg], s1[reg]);
#pragma unroll
            for (int d = 8; d >= 1; d >>= 1) m = fmaxf(m, __shfl_xor(m, d));
            mx[reg] = m;
            float e = __expf(s0[reg] - m) + __expf(s1[reg] - m);
#pragma unroll
            for (int d = 8; d >= 1; d >>= 1) e += __shfl_xor(e, d);
            se[reg] = __logf(e);
        }
#pragma unroll
        for (int reg = 0; reg < 4; reg++) {
            long t = mi * 16 + lg * 4 + reg;
            long base = (t * B_DIM + b) * 32;
            OUT[base + lr]      = s0[reg] - mx[reg] - se[reg];
            OUT[base + 16 + lr] = s1[reg] - mx[reg] - se[reg];
        }
    }
}

// ---------------------------------------------------------------------------
extern "C" void kernel_launch(void* const* d_in, const int* in_sizes, int n_in,
                              void* d_out, int out_size, void* d_ws, size_t ws_size,
                              hipStream_t stream)
{
    const float* X    = (const float*)d_in[0];   // [T,B,F]
    const float* adj  = (const float*)d_in[1];   // [B,B]
    const float* W1   = (const float*)d_in[2];   // [F,H1]
    const float* b1   = (const float*)d_in[3];
    const float* W2   = (const float*)d_in[4];   // [H1,H]
    const float* b2   = (const float*)d_in[5];
    const float* Win  = (const float*)d_in[6];   // [4,F+H,Q]
    const float* b_in = (const float*)d_in[7];   // [4,Q]
    const float* Wout = (const float*)d_in[8];   // [4,Q,H]
    const float* bout = (const float*)d_in[9];   // [4,H]
    const float* Wtag = (const float*)d_in[10];  // [H,TAGS]
    const float* btag = (const float*)d_in[11];
    float* OUT = (float*)d_out;

    float* ws = (float*)d_ws;
    float* NSP  = ws;                    // [T,B,16]  1,048,576 f
    float* adjT = ws + 1048576;          // [B,B]        65,536 f
    float* AX   = ws + 1114112;          // [T,B,16]  1,048,576 f
    unsigned short* W1p   = (unsigned short*)(ws + 2162688);   // 32768 bf16
    unsigned short* W2p   = W1p + 32768;                       // 32768 bf16
    unsigned short* Winxp = W2p + 32768;                       //  2048 bf16
    unsigned short* Wtagp = Winxp + 2048;                      //  4096 bf16

    prep_kernel<<<dim3(64), dim3(256), 0, stream>>>(W1, W2, Win, Wtag, W1p, W2p, Winxp, Wtagp);
    mlp_mfma_kernel<<<dim3(TB / 64), dim3(256), 0, stream>>>(X, W1p, b1, W2p, b2, Winxp, NSP);
    transpose_kernel<<<dim3(64), dim3(256), 0, stream>>>(adj, adjT);
    aggx_kernel<<<dim3(256), dim3(256), 0, stream>>>(adjT, NSP, b_in, AX);
    lstm_head_kernel<<<dim3(B_DIM), dim3(64), 0, stream>>>(AX, Win, Wout, bout, Wtagp, btag, OUT);
}

// Round 11
// 175.533 us; speedup vs baseline: 1.1934x; 1.0157x over previous
//
#include <hip/hip_runtime.h>
#include <hip/hip_bf16.h>

// Problem dims (fixed)
#define T_DIM 256
#define B_DIM 256
#define F_DIM 128
#define H1_DIM 256
#define H_DIM 128
#define Q_DIM 4
#define TAGS 32
#define TB (T_DIM * B_DIM)   // 65536 rows

typedef __attribute__((ext_vector_type(8))) short bf16x8;
typedef __attribute__((ext_vector_type(4))) float f32x4;

__device__ __forceinline__ float rcpf(float x) { return __builtin_amdgcn_rcpf(x); }
__device__ __forceinline__ float exp2f_hw(float x) { return __builtin_amdgcn_exp2f(x); }

// v_exp_f32 IS exp2: fold the 2x / -x scaling into the log2e constant.
__device__ __forceinline__ float tanhf_fast(float x) {
    float e = exp2f_hw(2.885390081777927f * x);   // exp(2x)
    return 1.0f - 2.0f * rcpf(e + 1.0f);
}
__device__ __forceinline__ float sigf(float x) {
    return rcpf(1.0f + exp2f_hw(-1.4426950408889634f * x));
}

__device__ __forceinline__ unsigned short f2bf(float f) {
    __hip_bfloat16 h = __float2bfloat16(f);   // RNE
    return *reinterpret_cast<unsigned short*>(&h);
}

// DPP cross-lane add within quad: CTRL=0xB1 -> lane^1, CTRL=0x4E -> lane^2
template<int CTRL>
__device__ __forceinline__ float dpp_xadd(float x) {
    int t = __builtin_amdgcn_update_dpp(0, __float_as_int(x), CTRL, 0xF, 0xF, true);
    return x + __int_as_float(t);
}

// ---------------------------------------------------------------------------
// Kernel 0: weight prep into MFMA B-fragment order (bf16).
// Wp[((kk*NB + nb)*64 + lane)*8 + e] = W[kk*32 + (lane>>4)*8 + e][nb*16 + (lane&15)]
// ---------------------------------------------------------------------------
__global__ __launch_bounds__(256) void prep_kernel(
    const float* __restrict__ W1, const float* __restrict__ W2,
    const float* __restrict__ Win, const float* __restrict__ Wtag,
    unsigned short* __restrict__ W1p, unsigned short* __restrict__ W2p,
    unsigned short* __restrict__ Winxp, unsigned short* __restrict__ Wtagp)
{
    const int gid0 = blockIdx.x * 256 + threadIdx.x;
    const int gstride = gridDim.x * 256;
    // W1p: K=128 (kk 0..3), N=256 (nb 0..15)
    for (int idx = gid0; idx < 32768; idx += gstride) {
        int e = idx & 7, l = (idx >> 3) & 63, t2 = idx >> 9;
        int nb = t2 & 15, kk = t2 >> 4;
        int k = kk * 32 + (l >> 4) * 8 + e, n = nb * 16 + (l & 15);
        W1p[idx] = f2bf(W1[k * 256 + n]);
    }
    // W2p: K=256 (kk 0..7), N=128 (nb 0..7)
    for (int idx = gid0; idx < 32768; idx += gstride) {
        int e = idx & 7, l = (idx >> 3) & 63, t2 = idx >> 9;
        int nb = t2 & 7, kk = t2 >> 3;
        int k = kk * 32 + (l >> 4) * 8 + e, n = nb * 16 + (l & 15);
        W2p[idx] = f2bf(W2[k * 128 + n]);
    }
    // Winxp: K=128 (kk 0..3), N=16. Winx[k][o] = Win[g][k][q], o=g*4+q
    for (int idx = gid0; idx < 2048; idx += gstride) {
        int e = idx & 7, l = (idx >> 3) & 63, kk = idx >> 9;
        int k = kk * 32 + (l >> 4) * 8 + e, o = l & 15;
        Winxp[idx] = f2bf(Win[(o >> 2) * 1024 + k * 4 + (o & 3)]);
    }
    // Wtagp: K=128 (kk 0..3), N=32 (nt 0..1)
    for (int idx = gid0; idx < 4096; idx += gstride) {
        int e = idx & 7, l = (idx >> 3) & 63, t2 = idx >> 9;
        int nt = t2 & 1, kk = t2 >> 1;
        int k = kk * 32 + (l >> 4) * 8 + e, n = nt * 16 + (l & 15);
        Wtagp[idx] = f2bf(Wtag[k * 32 + n]);
    }
}

// ---------------------------------------------------------------------------
// Kernel 1: MFMA MLP + fused Win_x projection.
// NSP[row,o] = tanh(tanh(X@W1+b1)@W2+b2) @ Winx[:,o]
// ---------------------------------------------------------------------------
__global__ __launch_bounds__(256) void mlp_mfma_kernel(
    const float* __restrict__ X, const unsigned short* __restrict__ W1p,
    const float* __restrict__ b1, const unsigned short* __restrict__ W2p,
    const float* __restrict__ b2, const unsigned short* __restrict__ Winxp,
    float* __restrict__ NSP)
{
    __shared__ __align__(16) unsigned short a1_s[64 * 256];   // 32 KB, stride 512 B
    __shared__ __align__(16) unsigned short xns_s[64 * 128];  // 16 KB: X, then ns

    const int tid = threadIdx.x;
    const int w = tid >> 6;
    const int lane = tid & 63;
    const int lr = lane & 15;
    const int lg = lane >> 4;
    const long rowbase = (long)blockIdx.x * 64;

    char* const a1c = (char*)a1_s;
    char* const xnc = (char*)xns_s;

    // ---- stage X tile (64x128 f32 -> bf16, swizzled) ----
    {
        const int r = tid >> 2;
        const int qc = tid & 3;
        const float4* xg = (const float4*)(X + (rowbase + r) * 128 + qc * 32);
#pragma unroll
        for (int i = 0; i < 4; i++) {
            float4 lo = xg[i * 2], hi = xg[i * 2 + 1];
            bf16x8 v;
            v[0] = (short)f2bf(lo.x); v[1] = (short)f2bf(lo.y);
            v[2] = (short)f2bf(lo.z); v[3] = (short)f2bf(lo.w);
            v[4] = (short)f2bf(hi.x); v[5] = (short)f2bf(hi.y);
            v[6] = (short)f2bf(hi.z); v[7] = (short)f2bf(hi.w);
            int byte = (r * 256 + qc * 64 + i * 16) ^ ((r & 7) << 4);
            *(bf16x8*)(xnc + byte) = v;
        }
    }
    __syncthreads();

    // ---- Phase A: a1 = tanh(X @ W1 + b1), wave w -> cols w*64..+63 ----
    {
        f32x4 acc[4][4];
#pragma unroll
        for (int mi = 0; mi < 4; mi++)
#pragma unroll
            for (int j = 0; j < 4; j++) acc[mi][j] = (f32x4){0.f, 0.f, 0.f, 0.f};

        const bf16x8* w1v = (const bf16x8*)W1p;
#pragma unroll
        for (int kk = 0; kk < 4; kk++) {
            bf16x8 af[4];
#pragma unroll
            for (int mi = 0; mi < 4; mi++) {
                int row = mi * 16 + lr;
                int byte = (row * 256 + kk * 64 + lg * 16) ^ ((row & 7) << 4);
                af[mi] = *(const bf16x8*)(xnc + byte);
            }
            bf16x8 bfv[4];
#pragma unroll
            for (int j = 0; j < 4; j++)
                bfv[j] = w1v[(kk * 16 + (w * 4 + j)) * 64 + lane];
#pragma unroll
            for (int mi = 0; mi < 4; mi++)
#pragma unroll
                for (int j = 0; j < 4; j++)
                    acc[mi][j] = __builtin_amdgcn_mfma_f32_16x16x32_bf16(
                        af[mi], bfv[j], acc[mi][j], 0, 0, 0);
        }

        float b1v[4];
#pragma unroll
        for (int j = 0; j < 4; j++) b1v[j] = b1[(w * 4 + j) * 16 + lr];
#pragma unroll
        for (int mi = 0; mi < 4; mi++)
#pragma unroll
            for (int j = 0; j < 4; j++)
#pragma unroll
                for (int reg = 0; reg < 4; reg++) {
                    int row = mi * 16 + lg * 4 + reg;
                    int col = (w * 4 + j) * 16 + lr;
                    float v = tanhf_fast(acc[mi][j][reg] + b1v[j]);
                    int byte = (row * 512 + col * 2) ^ ((row & 7) << 4);
                    *(unsigned short*)(a1c + byte) = f2bf(v);
                }
    }
    __syncthreads();

    // ---- Phase B: ns = tanh(a1 @ W2 + b2), wave w -> cols w*32..+31 ----
    {
        f32x4 acc[4][2];
#pragma unroll
        for (int mi = 0; mi < 4; mi++)
#pragma unroll
            for (int j = 0; j < 2; j++) acc[mi][j] = (f32x4){0.f, 0.f, 0.f, 0.f};

        const bf16x8* w2v = (const bf16x8*)W2p;
#pragma unroll
        for (int kk = 0; kk < 8; kk++) {
            bf16x8 af[4];
#pragma unroll
            for (int mi = 0; mi < 4; mi++) {
                int row = mi * 16 + lr;
                int byte = (row * 512 + kk * 64 + lg * 16) ^ ((row & 7) << 4);
                af[mi] = *(const bf16x8*)(a1c + byte);
            }
            bf16x8 bfv[2];
#pragma unroll
            for (int j = 0; j < 2; j++)
                bfv[j] = w2v[(kk * 8 + (w * 2 + j)) * 64 + lane];
#pragma unroll
            for (int mi = 0; mi < 4; mi++)
#pragma unroll
                for (int j = 0; j < 2; j++)
                    acc[mi][j] = __builtin_amdgcn_mfma_f32_16x16x32_bf16(
                        af[mi], bfv[j], acc[mi][j], 0, 0, 0);
        }

        float b2v[2];
#pragma unroll
        for (int j = 0; j < 2; j++) b2v[j] = b2[(w * 2 + j) * 16 + lr];
#pragma unroll
        for (int mi = 0; mi < 4; mi++)
#pragma unroll
            for (int j = 0; j < 2; j++)
#pragma unroll
                for (int reg = 0; reg < 4; reg++) {
                    int row = mi * 16 + lg * 4 + reg;
                    int col = (w * 2 + j) * 16 + lr;
                    float v = tanhf_fast(acc[mi][j][reg] + b2v[j]);
                    int byte = (row * 256 + col * 2) ^ ((row & 7) << 4);
                    *(unsigned short*)(xnc + byte) = f2bf(v);
                }
    }
    __syncthreads();

    // ---- NSP: nsp = ns @ Winx   (wave w -> rows w*16..+15) ----
    {
        f32x4 acc = (f32x4){0.f, 0.f, 0.f, 0.f};
        const bf16x8* wxv = (const bf16x8*)Winxp;
#pragma unroll
        for (int kk = 0; kk < 4; kk++) {
            int row = w * 16 + lr;
            int byte = (row * 256 + kk * 64 + lg * 16) ^ ((row & 7) << 4);
            bf16x8 af = *(const bf16x8*)(xnc + byte);
            bf16x8 bfv = wxv[kk * 64 + lane];
            acc = __builtin_amdgcn_mfma_f32_16x16x32_bf16(af, bfv, acc, 0, 0, 0);
        }
#pragma unroll
        for (int reg = 0; reg < 4; reg++) {
            int row = w * 16 + lg * 4 + reg;
            NSP[(rowbase + row) * 16 + lr] = acc[reg];
        }
    }
}

// ---------------------------------------------------------------------------
// Kernel 2: adj transpose. adjT[j][i] = adj[i][j]
// ---------------------------------------------------------------------------
__global__ __launch_bounds__(256) void transpose_kernel(
    const float* __restrict__ adj, float* __restrict__ adjT)
{
    __shared__ float tile[32][33];
    const int tid = threadIdx.x;
    const int bx = blockIdx.x & 7, by = blockIdx.x >> 3;
    const int lx = tid & 31, ly = (tid >> 5) * 4;
#pragma unroll
    for (int r = 0; r < 4; r++)
        tile[ly + r][lx] = adj[(long)(by * 32 + ly + r) * 256 + bx * 32 + lx];
    __syncthreads();
#pragma unroll
    for (int r = 0; r < 4; r++)
        adjT[(long)(bx * 32 + ly + r) * 256 + by * 32 + lx] = tile[lx][ly + r];
}

// ---------------------------------------------------------------------------
// Kernel 3: AX[t,i,o] = b_in[o] + sum_j adj[i,j] * NSP[t,j,o]
// ---------------------------------------------------------------------------
__global__ __launch_bounds__(256) void aggx_kernel(
    const float* __restrict__ adjT, const float* __restrict__ NSP,
    const float* __restrict__ b_in, float* __restrict__ AX)
{
    __shared__ float4 nsp_s[256 * 4];
    const int tid = threadIdx.x;
    const int t = blockIdx.x;
    {
        const float4* g = (const float4*)(NSP + (long)t * 4096);
#pragma unroll
        for (int i = 0; i < 4; i++) nsp_s[tid + i * 256] = g[tid + i * 256];
    }
    __syncthreads();

    float4 acc[4];
#pragma unroll
    for (int p = 0; p < 4; p++) acc[p] = ((const float4*)b_in)[p];

    const float* arow = adjT + tid;
    float a[8], an[8];
#pragma unroll
    for (int m = 0; m < 8; m++) an[m] = arow[m * 256];
    for (int j0 = 0; j0 < 256; j0 += 8) {
#pragma unroll
        for (int m = 0; m < 8; m++) a[m] = an[m];
        if (j0 + 8 < 256) {
#pragma unroll
            for (int m = 0; m < 8; m++) an[m] = arow[(j0 + 8 + m) * 256];
        }
#pragma unroll
        for (int m = 0; m < 8; m++) {
            float av = a[m];
#pragma unroll
            for (int p = 0; p < 4; p++) {
                float4 nv = nsp_s[(j0 + m) * 4 + p];
                acc[p].x += av * nv.x; acc[p].y += av * nv.y;
                acc[p].z += av * nv.z; acc[p].w += av * nv.w;
            }
        }
    }
    float4* out = (float4*)(AX + (long)t * 4096 + tid * 16);
#pragma unroll
    for (int p = 0; p < 4; p++) out[p] = acc[p];
}

// ---------------------------------------------------------------------------
// Kernel 4: LSTM scan + FUSED tag head. One wave per batch element.
// Round-11: 2-step unroll, unconditional distance-2 AX prefetch moved to the
// loop tail (after the hvhi reads) so its SALU/VMEM issue covers part of the
// lgkm wait at the loop top. AX over-reads 2 rows into the (initialized)
// weight-prep region; those values are never consumed.
// ---------------------------------------------------------------------------
__device__ __forceinline__ int hhoff(int row, int inrow) {
    return (row * 512 + inrow) ^ ((row & 7) << 4);
}

__global__ __attribute__((amdgpu_waves_per_eu(1, 1))) __launch_bounds__(64)
void lstm_head_kernel(
    const float* __restrict__ AX, const float* __restrict__ Win,
    const float* __restrict__ Wout, const float* __restrict__ b_out,
    const unsigned short* __restrict__ Wtagp, const float* __restrict__ btag,
    float* __restrict__ OUT)
{
    __shared__ __align__(16) float hh[T_DIM * 128];   // 128 KB, swizzled rows
    char* const hhc = (char*)hh;

    const int lane = threadIdx.x;
    const int b = blockIdx.x;
    const int o = lane >> 2;
    const int s = lane & 3;
    const int g_o = o >> 2, q_o = o & 3;

    // wh[m*4+j] = Win_h[k][o], k = m*16 + s*4 + j  (m<4: h[0..63], m>=4: h[64..127])
    float wh[32];
#pragma unroll
    for (int m = 0; m < 8; m++)
#pragma unroll
        for (int j = 0; j < 4; j++)
            wh[m * 4 + j] = Win[g_o * 1024 + 512 + (m * 16 + s * 4 + j) * 4 + q_o];

    float wo[4][4][2];
    float bo[4][2];
#pragma unroll
    for (int g = 0; g < 4; g++) {
#pragma unroll
        for (int h2 = 0; h2 < 2; h2++) bo[g][h2] = b_out[g * 128 + lane + 64 * h2];
#pragma unroll
        for (int q = 0; q < 4; q++)
#pragma unroll
            for (int h2 = 0; h2 < 2; h2++)
                wo[g][q][h2] = Wout[(g * 4 + q) * 128 + lane + 64 * h2];
    }

    float c0 = 0.f, c1 = 0.f;
    *(float*)(hhc + hhoff(255, lane * 4)) = 0.f;
    *(float*)(hhc + hhoff(255, 256 + lane * 4)) = 0.f;

    // prologue: preload h(-1) = zeros into the pipeline registers
    float4 hvlo[4], hvhi[4];
#pragma unroll
    for (int m = 0; m < 4; m++)
        hvlo[m] = *(const float4*)(hhc + hhoff(255, m * 64 + s * 16));
#pragma unroll
    for (int m = 0; m < 4; m++)
        hvhi[m] = *(const float4*)(hhc + hhoff(255, 256 + m * 64 + s * 16));

    // distance-2 AX prefetch, pointer-bump addressing (unconditional; the two
    // over-read rows land in the weight-prep region and are never consumed)
    const float* axp = AX + (long)b * 16 + o;
    float ax_cur = axp[0];
    float ax_nxt = axp[B_DIM * 16];
    axp += 2 * B_DIM * 16;

#pragma unroll 2
    for (int t = 0; t < T_DIM; t++) {
        // zpre from preloaded registers: 8 parallel chains, depth 4
        float a0 = hvlo[0].x*wh[0]  + hvlo[0].y*wh[1]  + hvlo[0].z*wh[2]  + hvlo[0].w*wh[3];
        float a1 = hvlo[1].x*wh[4]  + hvlo[1].y*wh[5]  + hvlo[1].z*wh[6]  + hvlo[1].w*wh[7];
        float a2 = hvlo[2].x*wh[8]  + hvlo[2].y*wh[9]  + hvlo[2].z*wh[10] + hvlo[2].w*wh[11];
        float a3 = hvlo[3].x*wh[12] + hvlo[3].y*wh[13] + hvlo[3].z*wh[14] + hvlo[3].w*wh[15];
        float a4 = hvhi[0].x*wh[16] + hvhi[0].y*wh[17] + hvhi[0].z*wh[18] + hvhi[0].w*wh[19];
        float a5 = hvhi[1].x*wh[20] + hvhi[1].y*wh[21] + hvhi[1].z*wh[22] + hvhi[1].w*wh[23];
        float a6 = hvhi[2].x*wh[24] + hvhi[2].y*wh[25] + hvhi[2].z*wh[26] + hvhi[2].w*wh[27];
        float a7 = hvhi[3].x*wh[28] + hvhi[3].y*wh[29] + hvhi[3].z*wh[30] + hvhi[3].w*wh[31];
        float acc = ((a0 + a1) + (a2 + a3)) + ((a4 + a5) + (a6 + a7));
        acc = dpp_xadd<0xB1>(acc);
        acc = dpp_xadd<0x4E>(acc);
        float zv = tanhf_fast(acc + ax_cur);

        unsigned zb = __float_as_uint(zv);
        float z[16];
#pragma unroll
        for (int oo = 0; oo < 16; oo++)
            z[oo] = __uint_as_float(__builtin_amdgcn_readlane(zb, oo * 4));

        // ---- half 0: gates -> h0 -> write -> ISSUE next low reads ----
        {
            float gp_f = bo[0][0] + z[0]*wo[0][0][0] + z[1]*wo[0][1][0] + z[2]*wo[0][2][0] + z[3]*wo[0][3][0];
            float gp_i = bo[1][0] + z[4]*wo[1][0][0] + z[5]*wo[1][1][0] + z[6]*wo[1][2][0] + z[7]*wo[1][3][0];
            float gp_g = bo[2][0] + z[8]*wo[2][0][0] + z[9]*wo[2][1][0] + z[10]*wo[2][2][0] + z[11]*wo[2][3][0];
            float gp_o = bo[3][0] + z[12]*wo[3][0][0] + z[13]*wo[3][1][0] + z[14]*wo[3][2][0] + z[15]*wo[3][3][0];
            float fg = sigf(gp_f);
            float ig = sigf(gp_i);
            float gg = tanhf_fast(gp_g);
            float og = sigf(gp_o);
            c0 = fg * c0 + ig * gg;
            float h0 = og * tanhf_fast(c0);
            *(float*)(hhc + hhoff(t, lane * 4)) = h0;
        }
        // early reads of the low half just written (hide latency under half 1)
#pragma unroll
        for (int m = 0; m < 4; m++)
            hvlo[m] = *(const float4*)(hhc + hhoff(t, m * 64 + s * 16));

        // ---- half 1: gates -> h1 -> write -> ISSUE next high reads ----
        {
            float gp_f = bo[0][1] + z[0]*wo[0][0][1] + z[1]*wo[0][1][1] + z[2]*wo[0][2][1] + z[3]*wo[0][3][1];
            float gp_i = bo[1][1] + z[4]*wo[1][0][1] + z[5]*wo[1][1][1] + z[6]*wo[1][2][1] + z[7]*wo[1][3][1];
            float gp_g = bo[2][1] + z[8]*wo[2][0][1] + z[9]*wo[2][1][1] + z[10]*wo[2][2][1] + z[11]*wo[2][3][1];
            float gp_o = bo[3][1] + z[12]*wo[3][0][1] + z[13]*wo[3][1][1] + z[14]*wo[3][2][1] + z[15]*wo[3][3][1];
            float fg = sigf(gp_f);
            float ig = sigf(gp_i);
            float gg = tanhf_fast(gp_g);
            float og = sigf(gp_o);
            c1 = fg * c1 + ig * gg;
            float h1 = og * tanhf_fast(c1);
            *(float*)(hhc + hhoff(t, 256 + lane * 4)) = h1;
        }
#pragma unroll
        for (int m = 0; m < 4; m++)
            hvhi[m] = *(const float4*)(hhc + hhoff(t, 256 + m * 64 + s * 16));

        // rotate distance-2 prefetch at the tail (issue covers loop-top waits)
        ax_cur = ax_nxt;
        ax_nxt = *axp;
        axp += B_DIM * 16;
    }

    // ================= fused tag head =================
    // logits[256t x 32tag] = hh @ Wtag + btag ; out = log_softmax(rows)
    const int lr = lane & 15;
    const int lg = lane >> 4;
    const bf16x8* wtv = (const bf16x8*)Wtagp;
    bf16x8 wt[4][2];
#pragma unroll
    for (int kk = 0; kk < 4; kk++)
#pragma unroll
        for (int nt = 0; nt < 2; nt++)
            wt[kk][nt] = wtv[(kk * 2 + nt) * 64 + lane];
    float bt0 = btag[lr], bt1 = btag[16 + lr];

    for (int mi = 0; mi < 16; mi++) {
        f32x4 acc0 = (f32x4){0.f, 0.f, 0.f, 0.f};
        f32x4 acc1 = (f32x4){0.f, 0.f, 0.f, 0.f};
        const int arow = mi * 16 + lr;
#pragma unroll
        for (int kk = 0; kk < 4; kk++) {
            float4 lo = *(const float4*)(hhc + hhoff(arow, kk * 128 + lg * 32));
            float4 hi = *(const float4*)(hhc + hhoff(arow, kk * 128 + lg * 32 + 16));
            bf16x8 af;
            af[0] = (short)f2bf(lo.x); af[1] = (short)f2bf(lo.y);
            af[2] = (short)f2bf(lo.z); af[3] = (short)f2bf(lo.w);
            af[4] = (short)f2bf(hi.x); af[5] = (short)f2bf(hi.y);
            af[6] = (short)f2bf(hi.z); af[7] = (short)f2bf(hi.w);
            acc0 = __builtin_amdgcn_mfma_f32_16x16x32_bf16(af, wt[kk][0], acc0, 0, 0, 0);
            acc1 = __builtin_amdgcn_mfma_f32_16x16x32_bf16(af, wt[kk][1], acc1, 0, 0, 0);
        }
        // per-row (over 32 tags) log_softmax. Row r = mi*16 + lg*4 + reg is
        // held by the 16 lanes of group lg (cols = lane&15).
        float s0[4], s1[4], mx[4], se[4];
#pragma unroll
        for (int reg = 0; reg < 4; reg++) {
            s0[reg] = acc0[reg] + bt0;
            s1[reg] = acc1[reg] + bt1;
            float m = fmaxf(s0[reg], s1[reg]);
#pragma unroll
            for (int d = 8; d >= 1; d >>= 1) m = fmaxf(m, __shfl_xor(m, d));
            mx[reg] = m;
            float e = __expf(s0[reg] - m) + __expf(s1[reg] - m);
#pragma unroll
            for (int d = 8; d >= 1; d >>= 1) e += __shfl_xor(e, d);
            se[reg] = __logf(e);
        }
#pragma unroll
        for (int reg = 0; reg < 4; reg++) {
            long t = mi * 16 + lg * 4 + reg;
            long base = (t * B_DIM + b) * 32;
            OUT[base + lr]      = s0[reg] - mx[reg] - se[reg];
            OUT[base + 16 + lr] = s1[reg] - mx[reg] - se[reg];
        }
    }
}

// ---------------------------------------------------------------------------
extern "C" void kernel_launch(void* const* d_in, const int* in_sizes, int n_in,
                              void* d_out, int out_size, void* d_ws, size_t ws_size,
                              hipStream_t stream)
{
    const float* X    = (const float*)d_in[0];   // [T,B,F]
    const float* adj  = (const float*)d_in[1];   // [B,B]
    const float* W1   = (const float*)d_in[2];   // [F,H1]
    const float* b1   = (const float*)d_in[3];
    const float* W2   = (const float*)d_in[4];   // [H1,H]
    const float* b2   = (const float*)d_in[5];
    const float* Win  = (const float*)d_in[6];   // [4,F+H,Q]
    const float* b_in = (const float*)d_in[7];   // [4,Q]
    const float* Wout = (const float*)d_in[8];   // [4,Q,H]
    const float* bout = (const float*)d_in[9];   // [4,H]
    const float* Wtag = (const float*)d_in[10];  // [H,TAGS]
    const float* btag = (const float*)d_in[11];
    float* OUT = (float*)d_out;

    float* ws = (float*)d_ws;
    float* NSP  = ws;                    // [T,B,16]  1,048,576 f
    float* adjT = ws + 1048576;          // [B,B]        65,536 f
    float* AX   = ws + 1114112;          // [T,B,16]  1,048,576 f (+2-row over-read
                                         //  slack lands in W1p region, never consumed)
    unsigned short* W1p   = (unsigned short*)(ws + 2162688);   // 32768 bf16
    unsigned short* W2p   = W1p + 32768;                       // 32768 bf16
    unsigned short* Winxp = W2p + 32768;                       //  2048 bf16
    unsigned short* Wtagp = Winxp + 2048;                      //  4096 bf16

    prep_kernel<<<dim3(64), dim3(256), 0, stream>>>(W1, W2, Win, Wtag, W1p, W2p, Winxp, Wtagp);
    mlp_mfma_kernel<<<dim3(TB / 64), dim3(256), 0, stream>>>(X, W1p, b1, W2p, b2, Winxp, NSP);
    transpose_kernel<<<dim3(64), dim3(256), 0, stream>>>(adj, adjT);
    aggx_kernel<<<dim3(256), dim3(256), 0, stream>>>(adjT, NSP, b_in, AX);
    lstm_head_kernel<<<dim3(B_DIM), dim3(64), 0, stream>>>(AX, Win, Wout, bout, Wtagp, btag, OUT);
}

// Round 12
// 157.200 us; speedup vs baseline: 1.3326x; 1.1166x over previous
//
#include <hip/hip_runtime.h>
#include <hip/hip_bf16.h>

// Problem dims (fixed)
#define T_DIM 256
#define B_DIM 256
#define F_DIM 128
#define H1_DIM 256
#define H_DIM 128
#define Q_DIM 4
#define TAGS 32
#define TB (T_DIM * B_DIM)   // 65536 rows

typedef __attribute__((ext_vector_type(8))) short bf16x8;
typedef __attribute__((ext_vector_type(4))) float f32x4;
typedef __attribute__((ext_vector_type(2))) float f32x2;

__device__ __forceinline__ float rcpf(float x) { return __builtin_amdgcn_rcpf(x); }
__device__ __forceinline__ float exp2f_hw(float x) { return __builtin_amdgcn_exp2f(x); }

// v_exp_f32 IS exp2: fold the 2x / -x scaling into the log2e constant.
__device__ __forceinline__ float tanhf_fast(float x) {
    float e = exp2f_hw(2.885390081777927f * x);   // exp(2x)
    return 1.0f - 2.0f * rcpf(e + 1.0f);
}
__device__ __forceinline__ float sigf(float x) {
    return rcpf(1.0f + exp2f_hw(-1.4426950408889634f * x));
}

__device__ __forceinline__ unsigned short f2bf(float f) {
    __hip_bfloat16 h = __float2bfloat16(f);   // RNE
    return *reinterpret_cast<unsigned short*>(&h);
}

// Packed f32 ops (VOP3P): 2 f32 lanes per instruction, full rate.
__device__ __forceinline__ f32x2 pk_mul2(f32x2 a, f32x2 b) {
    f32x2 d;
    asm("v_pk_mul_f32 %0, %1, %2" : "=v"(d) : "v"(a), "v"(b));
    return d;
}
__device__ __forceinline__ f32x2 pk_add2(f32x2 a, f32x2 b) {
    f32x2 d;
    asm("v_pk_add_f32 %0, %1, %2" : "=v"(d) : "v"(a), "v"(b));
    return d;
}
__device__ __forceinline__ f32x2 pk_fma2(f32x2 a, f32x2 b, f32x2 c) {
    f32x2 d;
    asm("v_pk_fma_f32 %0, %1, %2, %3" : "=v"(d) : "v"(a), "v"(b), "v"(c));
    return d;
}

// DPP cross-lane add within quad: CTRL=0xB1 -> lane^1, CTRL=0x4E -> lane^2
template<int CTRL>
__device__ __forceinline__ float dpp_xadd(float x) {
    int t = __builtin_amdgcn_update_dpp(0, __float_as_int(x), CTRL, 0xF, 0xF, true);
    return x + __int_as_float(t);
}

// ---------------------------------------------------------------------------
// Kernel 0: weight prep into MFMA B-fragment order (bf16).
// ---------------------------------------------------------------------------
__global__ __launch_bounds__(256) void prep_kernel(
    const float* __restrict__ W1, const float* __restrict__ W2,
    const float* __restrict__ Win, const float* __restrict__ Wtag,
    unsigned short* __restrict__ W1p, unsigned short* __restrict__ W2p,
    unsigned short* __restrict__ Winxp, unsigned short* __restrict__ Wtagp)
{
    const int gid0 = blockIdx.x * 256 + threadIdx.x;
    const int gstride = gridDim.x * 256;
    for (int idx = gid0; idx < 32768; idx += gstride) {
        int e = idx & 7, l = (idx >> 3) & 63, t2 = idx >> 9;
        int nb = t2 & 15, kk = t2 >> 4;
        int k = kk * 32 + (l >> 4) * 8 + e, n = nb * 16 + (l & 15);
        W1p[idx] = f2bf(W1[k * 256 + n]);
    }
    for (int idx = gid0; idx < 32768; idx += gstride) {
        int e = idx & 7, l = (idx >> 3) & 63, t2 = idx >> 9;
        int nb = t2 & 7, kk = t2 >> 3;
        int k = kk * 32 + (l >> 4) * 8 + e, n = nb * 16 + (l & 15);
        W2p[idx] = f2bf(W2[k * 128 + n]);
    }
    for (int idx = gid0; idx < 2048; idx += gstride) {
        int e = idx & 7, l = (idx >> 3) & 63, kk = idx >> 9;
        int k = kk * 32 + (l >> 4) * 8 + e, o = l & 15;
        Winxp[idx] = f2bf(Win[(o >> 2) * 1024 + k * 4 + (o & 3)]);
    }
    for (int idx = gid0; idx < 4096; idx += gstride) {
        int e = idx & 7, l = (idx >> 3) & 63, t2 = idx >> 9;
        int nt = t2 & 1, kk = t2 >> 1;
        int k = kk * 32 + (l >> 4) * 8 + e, n = nt * 16 + (l & 15);
        Wtagp[idx] = f2bf(Wtag[k * 32 + n]);
    }
}

// ---------------------------------------------------------------------------
// Kernel 1: MFMA MLP + fused Win_x projection.  (unchanged)
// ---------------------------------------------------------------------------
__global__ __launch_bounds__(256) void mlp_mfma_kernel(
    const float* __restrict__ X, const unsigned short* __restrict__ W1p,
    const float* __restrict__ b1, const unsigned short* __restrict__ W2p,
    const float* __restrict__ b2, const unsigned short* __restrict__ Winxp,
    float* __restrict__ NSP)
{
    __shared__ __align__(16) unsigned short a1_s[64 * 256];
    __shared__ __align__(16) unsigned short xns_s[64 * 128];

    const int tid = threadIdx.x;
    const int w = tid >> 6;
    const int lane = tid & 63;
    const int lr = lane & 15;
    const int lg = lane >> 4;
    const long rowbase = (long)blockIdx.x * 64;

    char* const a1c = (char*)a1_s;
    char* const xnc = (char*)xns_s;

    {
        const int r = tid >> 2;
        const int qc = tid & 3;
        const float4* xg = (const float4*)(X + (rowbase + r) * 128 + qc * 32);
#pragma unroll
        for (int i = 0; i < 4; i++) {
            float4 lo = xg[i * 2], hi = xg[i * 2 + 1];
            bf16x8 v;
            v[0] = (short)f2bf(lo.x); v[1] = (short)f2bf(lo.y);
            v[2] = (short)f2bf(lo.z); v[3] = (short)f2bf(lo.w);
            v[4] = (short)f2bf(hi.x); v[5] = (short)f2bf(hi.y);
            v[6] = (short)f2bf(hi.z); v[7] = (short)f2bf(hi.w);
            int byte = (r * 256 + qc * 64 + i * 16) ^ ((r & 7) << 4);
            *(bf16x8*)(xnc + byte) = v;
        }
    }
    __syncthreads();

    {
        f32x4 acc[4][4];
#pragma unroll
        for (int mi = 0; mi < 4; mi++)
#pragma unroll
            for (int j = 0; j < 4; j++) acc[mi][j] = (f32x4){0.f, 0.f, 0.f, 0.f};

        const bf16x8* w1v = (const bf16x8*)W1p;
#pragma unroll
        for (int kk = 0; kk < 4; kk++) {
            bf16x8 af[4];
#pragma unroll
            for (int mi = 0; mi < 4; mi++) {
                int row = mi * 16 + lr;
                int byte = (row * 256 + kk * 64 + lg * 16) ^ ((row & 7) << 4);
                af[mi] = *(const bf16x8*)(xnc + byte);
            }
            bf16x8 bfv[4];
#pragma unroll
            for (int j = 0; j < 4; j++)
                bfv[j] = w1v[(kk * 16 + (w * 4 + j)) * 64 + lane];
#pragma unroll
            for (int mi = 0; mi < 4; mi++)
#pragma unroll
                for (int j = 0; j < 4; j++)
                    acc[mi][j] = __builtin_amdgcn_mfma_f32_16x16x32_bf16(
                        af[mi], bfv[j], acc[mi][j], 0, 0, 0);
        }

        float b1v[4];
#pragma unroll
        for (int j = 0; j < 4; j++) b1v[j] = b1[(w * 4 + j) * 16 + lr];
#pragma unroll
        for (int mi = 0; mi < 4; mi++)
#pragma unroll
            for (int j = 0; j < 4; j++)
#pragma unroll
                for (int reg = 0; reg < 4; reg++) {
                    int row = mi * 16 + lg * 4 + reg;
                    int col = (w * 4 + j) * 16 + lr;
                    float v = tanhf_fast(acc[mi][j][reg] + b1v[j]);
                    int byte = (row * 512 + col * 2) ^ ((row & 7) << 4);
                    *(unsigned short*)(a1c + byte) = f2bf(v);
                }
    }
    __syncthreads();

    {
        f32x4 acc[4][2];
#pragma unroll
        for (int mi = 0; mi < 4; mi++)
#pragma unroll
            for (int j = 0; j < 2; j++) acc[mi][j] = (f32x4){0.f, 0.f, 0.f, 0.f};

        const bf16x8* w2v = (const bf16x8*)W2p;
#pragma unroll
        for (int kk = 0; kk < 8; kk++) {
            bf16x8 af[4];
#pragma unroll
            for (int mi = 0; mi < 4; mi++) {
                int row = mi * 16 + lr;
                int byte = (row * 512 + kk * 64 + lg * 16) ^ ((row & 7) << 4);
                af[mi] = *(const bf16x8*)(a1c + byte);
            }
            bf16x8 bfv[2];
#pragma unroll
            for (int j = 0; j < 2; j++)
                bfv[j] = w2v[(kk * 8 + (w * 2 + j)) * 64 + lane];
#pragma unroll
            for (int mi = 0; mi < 4; mi++)
#pragma unroll
                for (int j = 0; j < 2; j++)
                    acc[mi][j] = __builtin_amdgcn_mfma_f32_16x16x32_bf16(
                        af[mi], bfv[j], acc[mi][j], 0, 0, 0);
        }

        float b2v[2];
#pragma unroll
        for (int j = 0; j < 2; j++) b2v[j] = b2[(w * 2 + j) * 16 + lr];
#pragma unroll
        for (int mi = 0; mi < 4; mi++)
#pragma unroll
            for (int j = 0; j < 2; j++)
#pragma unroll
                for (int reg = 0; reg < 4; reg++) {
                    int row = mi * 16 + lg * 4 + reg;
                    int col = (w * 2 + j) * 16 + lr;
                    float v = tanhf_fast(acc[mi][j][reg] + b2v[j]);
                    int byte = (row * 256 + col * 2) ^ ((row & 7) << 4);
                    *(unsigned short*)(xnc + byte) = f2bf(v);
                }
    }
    __syncthreads();

    {
        f32x4 acc = (f32x4){0.f, 0.f, 0.f, 0.f};
        const bf16x8* wxv = (const bf16x8*)Winxp;
#pragma unroll
        for (int kk = 0; kk < 4; kk++) {
            int row = w * 16 + lr;
            int byte = (row * 256 + kk * 64 + lg * 16) ^ ((row & 7) << 4);
            bf16x8 af = *(const bf16x8*)(xnc + byte);
            bf16x8 bfv = wxv[kk * 64 + lane];
            acc = __builtin_amdgcn_mfma_f32_16x16x32_bf16(af, bfv, acc, 0, 0, 0);
        }
#pragma unroll
        for (int reg = 0; reg < 4; reg++) {
            int row = w * 16 + lg * 4 + reg;
            NSP[(rowbase + row) * 16 + lr] = acc[reg];
        }
    }
}

// ---------------------------------------------------------------------------
// Kernel 2: adj transpose. adjT[j][i] = adj[i][j]
// ---------------------------------------------------------------------------
__global__ __launch_bounds__(256) void transpose_kernel(
    const float* __restrict__ adj, float* __restrict__ adjT)
{
    __shared__ float tile[32][33];
    const int tid = threadIdx.x;
    const int bx = blockIdx.x & 7, by = blockIdx.x >> 3;
    const int lx = tid & 31, ly = (tid >> 5) * 4;
#pragma unroll
    for (int r = 0; r < 4; r++)
        tile[ly + r][lx] = adj[(long)(by * 32 + ly + r) * 256 + bx * 32 + lx];
    __syncthreads();
#pragma unroll
    for (int r = 0; r < 4; r++)
        adjT[(long)(bx * 32 + ly + r) * 256 + by * 32 + lx] = tile[lx][ly + r];
}

// ---------------------------------------------------------------------------
// Kernel 3: AX[t,i,o] = b_in[o] + sum_j adj[i,j] * NSP[t,j,o]
// ---------------------------------------------------------------------------
__global__ __launch_bounds__(256) void aggx_kernel(
    const float* __restrict__ adjT, const float* __restrict__ NSP,
    const float* __restrict__ b_in, float* __restrict__ AX)
{
    __shared__ float4 nsp_s[256 * 4];
    const int tid = threadIdx.x;
    const int t = blockIdx.x;
    {
        const float4* g = (const float4*)(NSP + (long)t * 4096);
#pragma unroll
        for (int i = 0; i < 4; i++) nsp_s[tid + i * 256] = g[tid + i * 256];
    }
    __syncthreads();

    float4 acc[4];
#pragma unroll
    for (int p = 0; p < 4; p++) acc[p] = ((const float4*)b_in)[p];

    const float* arow = adjT + tid;
    float a[8], an[8];
#pragma unroll
    for (int m = 0; m < 8; m++) an[m] = arow[m * 256];
    for (int j0 = 0; j0 < 256; j0 += 8) {
#pragma unroll
        for (int m = 0; m < 8; m++) a[m] = an[m];
        if (j0 + 8 < 256) {
#pragma unroll
            for (int m = 0; m < 8; m++) an[m] = arow[(j0 + 8 + m) * 256];
        }
#pragma unroll
        for (int m = 0; m < 8; m++) {
            float av = a[m];
#pragma unroll
            for (int p = 0; p < 4; p++) {
                float4 nv = nsp_s[(j0 + m) * 4 + p];
                acc[p].x += av * nv.x; acc[p].y += av * nv.y;
                acc[p].z += av * nv.z; acc[p].w += av * nv.w;
            }
        }
    }
    float4* out = (float4*)(AX + (long)t * 4096 + tid * 16);
#pragma unroll
    for (int p = 0; p < 4; p++) out[p] = acc[p];
}

// ---------------------------------------------------------------------------
// Kernel 4: LSTM scan + FUSED tag head. One wave per batch element.
// Round-12: scan is issue-bound (one wave = 1 instr / 2 cyc) -> cut instrs:
//  - unroll-8 with precomputed woffs/roffs; swizzle bits become compile-time
//    offset: immediates (removes ~20 addr-VALU/step)
//  - packed-f32 dot: v_pk_fma_f32 halves the dot FMA count; h read as b64 pairs
//  - half-split write->read pipeline kept (round-10 win)
// ---------------------------------------------------------------------------
__device__ __forceinline__ int hhoff(int row, int inrow) {
    return (row * 512 + inrow) ^ ((row & 7) << 4);
}

__global__ __attribute__((amdgpu_waves_per_eu(1, 1))) __launch_bounds__(64)
void lstm_head_kernel(
    const float* __restrict__ AX, const float* __restrict__ Win,
    const float* __restrict__ Wout, const float* __restrict__ b_out,
    const unsigned short* __restrict__ Wtagp, const float* __restrict__ btag,
    float* __restrict__ OUT)
{
    __shared__ __align__(16) float hh[T_DIM * 128];   // 128 KB, swizzled rows
    char* const hhc = (char*)hh;

    const int lane = threadIdx.x;
    const int b = blockIdx.x;
    const int o = lane >> 2;
    const int s = lane & 3;
    const int g_o = o >> 2, q_o = o & 3;

    // wh2[m*2+p] = (Win_h[k][o], Win_h[k+1][o]), k = m*16 + s*4 + p*2
    // (m 0..3 -> h[0..63] via slot s; m 4..7 -> h[64..127])
    f32x2 wh2[16];
#pragma unroll
    for (int m = 0; m < 8; m++)
#pragma unroll
        for (int p = 0; p < 2; p++) {
            int k0 = m * 16 + s * 4 + p * 2;
            f32x2 v;
            v.x = Win[g_o * 1024 + 512 + k0 * 4 + q_o];
            v.y = Win[g_o * 1024 + 512 + (k0 + 1) * 4 + q_o];
            wh2[m * 2 + p] = v;
        }

    float wo[4][4][2];
    float bo[4][2];
#pragma unroll
    for (int g = 0; g < 4; g++) {
#pragma unroll
        for (int h2 = 0; h2 < 2; h2++) bo[g][h2] = b_out[g * 128 + lane + 64 * h2];
#pragma unroll
        for (int q = 0; q < 4; q++)
#pragma unroll
            for (int h2 = 0; h2 < 2; h2++)
                wo[g][q][h2] = Wout[(g * 4 + q) * 128 + lane + 64 * h2];
    }

    // precomputed per-slot lane-part offsets (swizzle folded at compile time)
    int woffs[8], roffs[8];
#pragma unroll
    for (int sl = 0; sl < 8; sl++) {
        woffs[sl] = (lane * 4) ^ (sl << 4);
        roffs[sl] = (s * 16) ^ ((sl << 4) & 0x30);
    }

    float c0 = 0.f, c1 = 0.f;
    // h(-1) = 0: zero-init pipeline registers directly (no LDS prologue)
    f32x2 hl[8], hx[8];
#pragma unroll
    for (int m = 0; m < 8; m++) { hl[m] = (f32x2){0.f, 0.f}; hx[m] = (f32x2){0.f, 0.f}; }

    // distance-2 AX prefetch (unconditional; over-read lands in weight region)
    const float* axp = AX + (long)b * 16 + o;
    float ax_cur = axp[0];
    float ax_nxt = axp[B_DIM * 16];
    axp += 2 * B_DIM * 16;

    int vbase = 0;   // byte offset of row tb
    for (int tb = 0; tb < T_DIM; tb += 8) {
#pragma unroll
        for (int sl = 0; sl < 8; sl++) {
            const int sw6 = (sl << 4) & 0x40;
            // ---- packed dot: 16 pk_fma over preloaded h pairs ----
            f32x2 aA = pk_mul2(hl[0], wh2[0]);
            f32x2 aB = pk_mul2(hl[1], wh2[1]);
            f32x2 aC = pk_mul2(hl[2], wh2[2]);
            f32x2 aD = pk_mul2(hl[3], wh2[3]);
            aA = pk_fma2(hl[4], wh2[4], aA);
            aB = pk_fma2(hl[5], wh2[5], aB);
            aC = pk_fma2(hl[6], wh2[6], aC);
            aD = pk_fma2(hl[7], wh2[7], aD);
            aA = pk_fma2(hx[0], wh2[8],  aA);
            aB = pk_fma2(hx[1], wh2[9],  aB);
            aC = pk_fma2(hx[2], wh2[10], aC);
            aD = pk_fma2(hx[3], wh2[11], aD);
            aA = pk_fma2(hx[4], wh2[12], aA);
            aB = pk_fma2(hx[5], wh2[13], aB);
            aC = pk_fma2(hx[6], wh2[14], aC);
            aD = pk_fma2(hx[7], wh2[15], aD);
            f32x2 sAB = pk_add2(aA, aB);
            f32x2 sCD = pk_add2(aC, aD);
            f32x2 sS  = pk_add2(sAB, sCD);
            float acc = sS.x + sS.y;
            acc = dpp_xadd<0xB1>(acc);
            acc = dpp_xadd<0x4E>(acc);
            float zv = tanhf_fast(acc + ax_cur);

            unsigned zb = __float_as_uint(zv);
            float z[16];
#pragma unroll
            for (int oo = 0; oo < 16; oo++)
                z[oo] = __uint_as_float(__builtin_amdgcn_readlane(zb, oo * 4));

            char* const wp = hhc + (vbase + woffs[sl]);       // write base (row tb+sl)
            const char* const rp = hhc + (vbase + roffs[sl]); // read base (row tb+sl)

            // ---- half 0: gates -> h0 -> write -> issue low reads ----
            {
                float gp_f = bo[0][0] + z[0]*wo[0][0][0] + z[1]*wo[0][1][0] + z[2]*wo[0][2][0] + z[3]*wo[0][3][0];
                float gp_i = bo[1][0] + z[4]*wo[1][0][0] + z[5]*wo[1][1][0] + z[6]*wo[1][2][0] + z[7]*wo[1][3][0];
                float gp_g = bo[2][0] + z[8]*wo[2][0][0] + z[9]*wo[2][1][0] + z[10]*wo[2][2][0] + z[11]*wo[2][3][0];
                float gp_o = bo[3][0] + z[12]*wo[3][0][0] + z[13]*wo[3][1][0] + z[14]*wo[3][2][0] + z[15]*wo[3][3][0];
                float fg = sigf(gp_f);
                float ig = sigf(gp_i);
                float gg = tanhf_fast(gp_g);
                float og = sigf(gp_o);
                c0 = fg * c0 + ig * gg;
                float h0 = og * tanhf_fast(c0);
                *(float*)(wp + sl * 512) = h0;
            }
#pragma unroll
            for (int m = 0; m < 4; m++) {
                hl[m * 2]     = *(const f32x2*)(rp + sl * 512 + ((m * 64) ^ sw6));
                hl[m * 2 + 1] = *(const f32x2*)(rp + sl * 512 + ((m * 64) ^ sw6) + 8);
            }

            // ---- half 1: gates -> h1 -> write -> issue high reads ----
            {
                float gp_f = bo[0][1] + z[0]*wo[0][0][1] + z[1]*wo[0][1][1] + z[2]*wo[0][2][1] + z[3]*wo[0][3][1];
                float gp_i = bo[1][1] + z[4]*wo[1][0][1] + z[5]*wo[1][1][1] + z[6]*wo[1][2][1] + z[7]*wo[1][3][1];
                float gp_g = bo[2][1] + z[8]*wo[2][0][1] + z[9]*wo[2][1][1] + z[10]*wo[2][2][1] + z[11]*wo[2][3][1];
                float gp_o = bo[3][1] + z[12]*wo[3][0][1] + z[13]*wo[3][1][1] + z[14]*wo[3][2][1] + z[15]*wo[3][3][1];
                float fg = sigf(gp_f);
                float ig = sigf(gp_i);
                float gg = tanhf_fast(gp_g);
                float og = sigf(gp_o);
                c1 = fg * c1 + ig * gg;
                float h1 = og * tanhf_fast(c1);
                *(float*)(wp + sl * 512 + 256) = h1;
            }
#pragma unroll
            for (int m = 0; m < 4; m++) {
                hx[m * 2]     = *(const f32x2*)(rp + sl * 512 + 256 + ((m * 64) ^ sw6));
                hx[m * 2 + 1] = *(const f32x2*)(rp + sl * 512 + 256 + ((m * 64) ^ sw6) + 8);
            }

            // rotate distance-2 prefetch at the tail
            ax_cur = ax_nxt;
            ax_nxt = *axp;
            axp += B_DIM * 16;
        }
        vbase += 8 * 512;
    }

    // ================= fused tag head =================
    const int lr = lane & 15;
    const int lg = lane >> 4;
    const bf16x8* wtv = (const bf16x8*)Wtagp;
    bf16x8 wt[4][2];
#pragma unroll
    for (int kk = 0; kk < 4; kk++)
#pragma unroll
        for (int nt = 0; nt < 2; nt++)
            wt[kk][nt] = wtv[(kk * 2 + nt) * 64 + lane];
    float bt0 = btag[lr], bt1 = btag[16 + lr];

    for (int mi = 0; mi < 16; mi++) {
        f32x4 acc0 = (f32x4){0.f, 0.f, 0.f, 0.f};
        f32x4 acc1 = (f32x4){0.f, 0.f, 0.f, 0.f};
        const int arow = mi * 16 + lr;
#pragma unroll
        for (int kk = 0; kk < 4; kk++) {
            float4 lo = *(const float4*)(hhc + hhoff(arow, kk * 128 + lg * 32));
            float4 hi = *(const float4*)(hhc + hhoff(arow, kk * 128 + lg * 32 + 16));
            bf16x8 af;
            af[0] = (short)f2bf(lo.x); af[1] = (short)f2bf(lo.y);
            af[2] = (short)f2bf(lo.z); af[3] = (short)f2bf(lo.w);
            af[4] = (short)f2bf(hi.x); af[5] = (short)f2bf(hi.y);
            af[6] = (short)f2bf(hi.z); af[7] = (short)f2bf(hi.w);
            acc0 = __builtin_amdgcn_mfma_f32_16x16x32_bf16(af, wt[kk][0], acc0, 0, 0, 0);
            acc1 = __builtin_amdgcn_mfma_f32_16x16x32_bf16(af, wt[kk][1], acc1, 0, 0, 0);
        }
        float s0[4], s1[4], mx[4], se[4];
#pragma unroll
        for (int reg = 0; reg < 4; reg++) {
            s0[reg] = acc0[reg] + bt0;
            s1[reg] = acc1[reg] + bt1;
            float m = fmaxf(s0[reg], s1[reg]);
#pragma unroll
            for (int d = 8; d >= 1; d >>= 1) m = fmaxf(m, __shfl_xor(m, d));
            mx[reg] = m;
            float e = __expf(s0[reg] - m) + __expf(s1[reg] - m);
#pragma unroll
            for (int d = 8; d >= 1; d >>= 1) e += __shfl_xor(e, d);
            se[reg] = __logf(e);
        }
#pragma unroll
        for (int reg = 0; reg < 4; reg++) {
            long t = mi * 16 + lg * 4 + reg;
            long base = (t * B_DIM + b) * 32;
            OUT[base + lr]      = s0[reg] - mx[reg] - se[reg];
            OUT[base + 16 + lr] = s1[reg] - mx[reg] - se[reg];
        }
    }
}

// ---------------------------------------------------------------------------
extern "C" void kernel_launch(void* const* d_in, const int* in_sizes, int n_in,
                              void* d_out, int out_size, void* d_ws, size_t ws_size,
                              hipStream_t stream)
{
    const float* X    = (const float*)d_in[0];   // [T,B,F]
    const float* adj  = (const float*)d_in[1];   // [B,B]
    const float* W1   = (const float*)d_in[2];   // [F,H1]
    const float* b1   = (const float*)d_in[3];
    const float* W2   = (const float*)d_in[4];   // [H1,H]
    const float* b2   = (const float*)d_in[5];
    const float* Win  = (const float*)d_in[6];   // [4,F+H,Q]
    const float* b_in = (const float*)d_in[7];   // [4,Q]
    const float* Wout = (const float*)d_in[8];   // [4,Q,H]
    const float* bout = (const float*)d_in[9];   // [4,H]
    const float* Wtag = (const float*)d_in[10];  // [H,TAGS]
    const float* btag = (const float*)d_in[11];
    float* OUT = (float*)d_out;

    float* ws = (float*)d_ws;
    float* NSP  = ws;                    // [T,B,16]  1,048,576 f
    float* adjT = ws + 1048576;          // [B,B]        65,536 f
    float* AX   = ws + 1114112;          // [T,B,16]  1,048,576 f (+over-read slack
                                         //  lands in W1p region, never consumed)
    unsigned short* W1p   = (unsigned short*)(ws + 2162688);   // 32768 bf16
    unsigned short* W2p   = W1p + 32768;                       // 32768 bf16
    unsigned short* Winxp = W2p + 32768;                       //  2048 bf16
    unsigned short* Wtagp = Winxp + 2048;                      //  4096 bf16

    prep_kernel<<<dim3(64), dim3(256), 0, stream>>>(W1, W2, Win, Wtag, W1p, W2p, Winxp, Wtagp);
    mlp_mfma_kernel<<<dim3(TB / 64), dim3(256), 0, stream>>>(X, W1p, b1, W2p, b2, Winxp, NSP);
    transpose_kernel<<<dim3(64), dim3(256), 0, stream>>>(adj, adjT);
    aggx_kernel<<<dim3(256), dim3(256), 0, stream>>>(adjT, NSP, b_in, AX);
    lstm_head_kernel<<<dim3(B_DIM), dim3(64), 0, stream>>>(AX, Win, Wout, bout, Wtagp, btag, OUT);
}

// Round 13
// 139.040 us; speedup vs baseline: 1.5066x; 1.1306x over previous
//
#include <hip/hip_runtime.h>
#include <hip/hip_bf16.h>

// Problem dims (fixed)
#define T_DIM 256
#define B_DIM 256
#define F_DIM 128
#define H1_DIM 256
#define H_DIM 128
#define Q_DIM 4
#define TAGS 32
#define TB (T_DIM * B_DIM)   // 65536 rows

typedef __attribute__((ext_vector_type(8))) short bf16x8;
typedef __attribute__((ext_vector_type(4))) float f32x4;
typedef __attribute__((ext_vector_type(2))) float f32x2;

__device__ __forceinline__ float rcpf(float x) { return __builtin_amdgcn_rcpf(x); }
__device__ __forceinline__ float exp2f_hw(float x) { return __builtin_amdgcn_exp2f(x); }

__device__ __forceinline__ float tanhf_fast(float x) {
    float e = exp2f_hw(2.885390081777927f * x);   // exp(2x)
    return 1.0f - 2.0f * rcpf(e + 1.0f);
}
__device__ __forceinline__ float sigf(float x) {
    return rcpf(1.0f + exp2f_hw(-1.4426950408889634f * x));
}

__device__ __forceinline__ unsigned short f2bf(float f) {
    __hip_bfloat16 h = __float2bfloat16(f);   // RNE
    return *reinterpret_cast<unsigned short*>(&h);
}

// Packed f32 ops (VOP3P): 2 f32 lanes per instruction.
__device__ __forceinline__ f32x2 pk_mul2(f32x2 a, f32x2 b) {
    f32x2 d;
    asm("v_pk_mul_f32 %0, %1, %2" : "=v"(d) : "v"(a), "v"(b));
    return d;
}
__device__ __forceinline__ f32x2 pk_add2(f32x2 a, f32x2 b) {
    f32x2 d;
    asm("v_pk_add_f32 %0, %1, %2" : "=v"(d) : "v"(a), "v"(b));
    return d;
}
__device__ __forceinline__ f32x2 pk_fma2(f32x2 a, f32x2 b, f32x2 c) {
    f32x2 d;
    asm("v_pk_fma_f32 %0, %1, %2, %3" : "=v"(d) : "v"(a), "v"(b), "v"(c));
    return d;
}

// DPP cross-lane add within quad: CTRL=0xB1 -> lane^1, CTRL=0x4E -> lane^2
template<int CTRL>
__device__ __forceinline__ float dpp_xadd(float x) {
    int t = __builtin_amdgcn_update_dpp(0, __float_as_int(x), CTRL, 0xF, 0xF, true);
    return x + __int_as_float(t);
}

// ---------------------------------------------------------------------------
// Kernel 0: weight prep into MFMA B-fragment order (bf16).
// ---------------------------------------------------------------------------
__global__ __launch_bounds__(256) void prep_kernel(
    const float* __restrict__ W1, const float* __restrict__ W2,
    const float* __restrict__ Win, const float* __restrict__ Wtag,
    unsigned short* __restrict__ W1p, unsigned short* __restrict__ W2p,
    unsigned short* __restrict__ Winxp, unsigned short* __restrict__ Wtagp)
{
    const int gid0 = blockIdx.x * 256 + threadIdx.x;
    const int gstride = gridDim.x * 256;
    for (int idx = gid0; idx < 32768; idx += gstride) {
        int e = idx & 7, l = (idx >> 3) & 63, t2 = idx >> 9;
        int nb = t2 & 15, kk = t2 >> 4;
        int k = kk * 32 + (l >> 4) * 8 + e, n = nb * 16 + (l & 15);
        W1p[idx] = f2bf(W1[k * 256 + n]);
    }
    for (int idx = gid0; idx < 32768; idx += gstride) {
        int e = idx & 7, l = (idx >> 3) & 63, t2 = idx >> 9;
        int nb = t2 & 7, kk = t2 >> 3;
        int k = kk * 32 + (l >> 4) * 8 + e, n = nb * 16 + (l & 15);
        W2p[idx] = f2bf(W2[k * 128 + n]);
    }
    for (int idx = gid0; idx < 2048; idx += gstride) {
        int e = idx & 7, l = (idx >> 3) & 63, kk = idx >> 9;
        int k = kk * 32 + (l >> 4) * 8 + e, o = l & 15;
        Winxp[idx] = f2bf(Win[(o >> 2) * 1024 + k * 4 + (o & 3)]);
    }
    for (int idx = gid0; idx < 4096; idx += gstride) {
        int e = idx & 7, l = (idx >> 3) & 63, t2 = idx >> 9;
        int nt = t2 & 1, kk = t2 >> 1;
        int k = kk * 32 + (l >> 4) * 8 + e, n = nt * 16 + (l & 15);
        Wtagp[idx] = f2bf(Wtag[k * 32 + n]);
    }
}

// ---------------------------------------------------------------------------
// Kernel 1: MFMA MLP + fused Win_x projection.  (unchanged)
// ---------------------------------------------------------------------------
__global__ __launch_bounds__(256) void mlp_mfma_kernel(
    const float* __restrict__ X, const unsigned short* __restrict__ W1p,
    const float* __restrict__ b1, const unsigned short* __restrict__ W2p,
    const float* __restrict__ b2, const unsigned short* __restrict__ Winxp,
    float* __restrict__ NSP)
{
    __shared__ __align__(16) unsigned short a1_s[64 * 256];
    __shared__ __align__(16) unsigned short xns_s[64 * 128];

    const int tid = threadIdx.x;
    const int w = tid >> 6;
    const int lane = tid & 63;
    const int lr = lane & 15;
    const int lg = lane >> 4;
    const long rowbase = (long)blockIdx.x * 64;

    char* const a1c = (char*)a1_s;
    char* const xnc = (char*)xns_s;

    {
        const int r = tid >> 2;
        const int qc = tid & 3;
        const float4* xg = (const float4*)(X + (rowbase + r) * 128 + qc * 32);
#pragma unroll
        for (int i = 0; i < 4; i++) {
            float4 lo = xg[i * 2], hi = xg[i * 2 + 1];
            bf16x8 v;
            v[0] = (short)f2bf(lo.x); v[1] = (short)f2bf(lo.y);
            v[2] = (short)f2bf(lo.z); v[3] = (short)f2bf(lo.w);
            v[4] = (short)f2bf(hi.x); v[5] = (short)f2bf(hi.y);
            v[6] = (short)f2bf(hi.z); v[7] = (short)f2bf(hi.w);
            int byte = (r * 256 + qc * 64 + i * 16) ^ ((r & 7) << 4);
            *(bf16x8*)(xnc + byte) = v;
        }
    }
    __syncthreads();

    {
        f32x4 acc[4][4];
#pragma unroll
        for (int mi = 0; mi < 4; mi++)
#pragma unroll
            for (int j = 0; j < 4; j++) acc[mi][j] = (f32x4){0.f, 0.f, 0.f, 0.f};

        const bf16x8* w1v = (const bf16x8*)W1p;
#pragma unroll
        for (int kk = 0; kk < 4; kk++) {
            bf16x8 af[4];
#pragma unroll
            for (int mi = 0; mi < 4; mi++) {
                int row = mi * 16 + lr;
                int byte = (row * 256 + kk * 64 + lg * 16) ^ ((row & 7) << 4);
                af[mi] = *(const bf16x8*)(xnc + byte);
            }
            bf16x8 bfv[4];
#pragma unroll
            for (int j = 0; j < 4; j++)
                bfv[j] = w1v[(kk * 16 + (w * 4 + j)) * 64 + lane];
#pragma unroll
            for (int mi = 0; mi < 4; mi++)
#pragma unroll
                for (int j = 0; j < 4; j++)
                    acc[mi][j] = __builtin_amdgcn_mfma_f32_16x16x32_bf16(
                        af[mi], bfv[j], acc[mi][j], 0, 0, 0);
        }

        float b1v[4];
#pragma unroll
        for (int j = 0; j < 4; j++) b1v[j] = b1[(w * 4 + j) * 16 + lr];
#pragma unroll
        for (int mi = 0; mi < 4; mi++)
#pragma unroll
            for (int j = 0; j < 4; j++)
#pragma unroll
                for (int reg = 0; reg < 4; reg++) {
                    int row = mi * 16 + lg * 4 + reg;
                    int col = (w * 4 + j) * 16 + lr;
                    float v = tanhf_fast(acc[mi][j][reg] + b1v[j]);
                    int byte = (row * 512 + col * 2) ^ ((row & 7) << 4);
                    *(unsigned short*)(a1c + byte) = f2bf(v);
                }
    }
    __syncthreads();

    {
        f32x4 acc[4][2];
#pragma unroll
        for (int mi = 0; mi < 4; mi++)
#pragma unroll
            for (int j = 0; j < 2; j++) acc[mi][j] = (f32x4){0.f, 0.f, 0.f, 0.f};

        const bf16x8* w2v = (const bf16x8*)W2p;
#pragma unroll
        for (int kk = 0; kk < 8; kk++) {
            bf16x8 af[4];
#pragma unroll
            for (int mi = 0; mi < 4; mi++) {
                int row = mi * 16 + lr;
                int byte = (row * 512 + kk * 64 + lg * 16) ^ ((row & 7) << 4);
                af[mi] = *(const bf16x8*)(a1c + byte);
            }
            bf16x8 bfv[2];
#pragma unroll
            for (int j = 0; j < 2; j++)
                bfv[j] = w2v[(kk * 8 + (w * 2 + j)) * 64 + lane];
#pragma unroll
            for (int mi = 0; mi < 4; mi++)
#pragma unroll
                for (int j = 0; j < 2; j++)
                    acc[mi][j] = __builtin_amdgcn_mfma_f32_16x16x32_bf16(
                        af[mi], bfv[j], acc[mi][j], 0, 0, 0);
        }

        float b2v[2];
#pragma unroll
        for (int j = 0; j < 2; j++) b2v[j] = b2[(w * 2 + j) * 16 + lr];
#pragma unroll
        for (int mi = 0; mi < 4; mi++)
#pragma unroll
            for (int j = 0; j < 2; j++)
#pragma unroll
                for (int reg = 0; reg < 4; reg++) {
                    int row = mi * 16 + lg * 4 + reg;
                    int col = (w * 2 + j) * 16 + lr;
                    float v = tanhf_fast(acc[mi][j][reg] + b2v[j]);
                    int byte = (row * 256 + col * 2) ^ ((row & 7) << 4);
                    *(unsigned short*)(xnc + byte) = f2bf(v);
                }
    }
    __syncthreads();

    {
        f32x4 acc = (f32x4){0.f, 0.f, 0.f, 0.f};
        const bf16x8* wxv = (const bf16x8*)Winxp;
#pragma unroll
        for (int kk = 0; kk < 4; kk++) {
            int row = w * 16 + lr;
            int byte = (row * 256 + kk * 64 + lg * 16) ^ ((row & 7) << 4);
            bf16x8 af = *(const bf16x8*)(xnc + byte);
            bf16x8 bfv = wxv[kk * 64 + lane];
            acc = __builtin_amdgcn_mfma_f32_16x16x32_bf16(af, bfv, acc, 0, 0, 0);
        }
#pragma unroll
        for (int reg = 0; reg < 4; reg++) {
            int row = w * 16 + lg * 4 + reg;
            NSP[(rowbase + row) * 16 + lr] = acc[reg];
        }
    }
}

// ---------------------------------------------------------------------------
// Kernel 2: adj transpose. adjT[j][i] = adj[i][j]
// ---------------------------------------------------------------------------
__global__ __launch_bounds__(256) void transpose_kernel(
    const float* __restrict__ adj, float* __restrict__ adjT)
{
    __shared__ float tile[32][33];
    const int tid = threadIdx.x;
    const int bx = blockIdx.x & 7, by = blockIdx.x >> 3;
    const int lx = tid & 31, ly = (tid >> 5) * 4;
#pragma unroll
    for (int r = 0; r < 4; r++)
        tile[ly + r][lx] = adj[(long)(by * 32 + ly + r) * 256 + bx * 32 + lx];
    __syncthreads();
#pragma unroll
    for (int r = 0; r < 4; r++)
        adjT[(long)(bx * 32 + ly + r) * 256 + by * 32 + lx] = tile[lx][ly + r];
}

// ---------------------------------------------------------------------------
// Kernel 3: AX[t,i,o] = b_in[o] + sum_j adj[i,j] * NSP[t,j,o]
// ---------------------------------------------------------------------------
__global__ __launch_bounds__(256) void aggx_kernel(
    const float* __restrict__ adjT, const float* __restrict__ NSP,
    const float* __restrict__ b_in, float* __restrict__ AX)
{
    __shared__ float4 nsp_s[256 * 4];
    const int tid = threadIdx.x;
    const int t = blockIdx.x;
    {
        const float4* g = (const float4*)(NSP + (long)t * 4096);
#pragma unroll
        for (int i = 0; i < 4; i++) nsp_s[tid + i * 256] = g[tid + i * 256];
    }
    __syncthreads();

    float4 acc[4];
#pragma unroll
    for (int p = 0; p < 4; p++) acc[p] = ((const float4*)b_in)[p];

    const float* arow = adjT + tid;
    float a[8], an[8];
#pragma unroll
    for (int m = 0; m < 8; m++) an[m] = arow[m * 256];
    for (int j0 = 0; j0 < 256; j0 += 8) {
#pragma unroll
        for (int m = 0; m < 8; m++) a[m] = an[m];
        if (j0 + 8 < 256) {
#pragma unroll
            for (int m = 0; m < 8; m++) an[m] = arow[(j0 + 8 + m) * 256];
        }
#pragma unroll
        for (int m = 0; m < 8; m++) {
            float av = a[m];
#pragma unroll
            for (int p = 0; p < 4; p++) {
                float4 nv = nsp_s[(j0 + m) * 4 + p];
                acc[p].x += av * nv.x; acc[p].y += av * nv.y;
                acc[p].z += av * nv.z; acc[p].w += av * nv.w;
            }
        }
    }
    float4* out = (float4*)(AX + (long)t * 4096 + tid * 16);
#pragma unroll
    for (int p = 0; p < 4; p++) out[p] = acc[p];
}

// ---------------------------------------------------------------------------
// Kernel 4: LSTM scan + FUSED tag head. TWO waves per batch element:
// the scan is single-wave issue-bound (~1 instr/2cyc), so split the gate
// work (the bulk) across 2 SIMDs. Each wave computes the z-dot redundantly
// (h is shared in LDS) but only one 64-feature half of the gates. One
// __syncthreads per step makes the halves visible cross-wave; AX prefetch
// rotates right after the barrier so the vmcnt drain is already satisfied.
// ---------------------------------------------------------------------------
__device__ __forceinline__ int hhoff(int row, int inrow) {
    return (row * 512 + inrow) ^ ((row & 7) << 4);
}

__global__ __attribute__((amdgpu_waves_per_eu(1, 1))) __launch_bounds__(128)
void lstm_head_kernel(
    const float* __restrict__ AX, const float* __restrict__ Win,
    const float* __restrict__ Wout, const float* __restrict__ b_out,
    const unsigned short* __restrict__ Wtagp, const float* __restrict__ btag,
    float* __restrict__ OUT)
{
    __shared__ __align__(16) float hh[T_DIM * 128];   // 128 KB, swizzled rows
    char* const hhc = (char*)hh;

    const int tid = threadIdx.x;
    const int w = tid >> 6;        // wave: h-half owner
    const int lane = tid & 63;
    const int b = blockIdx.x;
    const int o = lane >> 2;
    const int s = lane & 3;
    const int g_o = o >> 2, q_o = o & 3;

    // dot weights (same in both waves): wh2[m*2+p] = Win_h[k..k+1][o], k=m*16+s*4+p*2
    f32x2 wh2[16];
#pragma unroll
    for (int m = 0; m < 8; m++)
#pragma unroll
        for (int p = 0; p < 2; p++) {
            int k0 = m * 16 + s * 4 + p * 2;
            f32x2 v;
            v.x = Win[g_o * 1024 + 512 + k0 * 4 + q_o];
            v.y = Win[g_o * 1024 + 512 + (k0 + 1) * 4 + q_o];
            wh2[m * 2 + p] = v;
        }

    // gate weights for THIS wave's feature f = w*64 + lane
    const int f = w * 64 + lane;
    float wo[4][4];
    float bo[4];
#pragma unroll
    for (int g = 0; g < 4; g++) {
        bo[g] = b_out[g * 128 + f];
#pragma unroll
        for (int q = 0; q < 4; q++)
            wo[g][q] = Wout[(g * 4 + q) * 128 + f];
    }

    // per-slot offsets (swizzle folded to compile-time patterns)
    int woffs[8], roffs[8];
#pragma unroll
    for (int sl = 0; sl < 8; sl++) {
        woffs[sl] = ((lane * 4) ^ (sl << 4)) + w * 256;
        roffs[sl] = (s * 16) ^ ((sl << 4) & 0x30);
    }

    float c = 0.f;
    f32x2 hl[8], hx[8];
#pragma unroll
    for (int m = 0; m < 8; m++) { hl[m] = (f32x2){0.f, 0.f}; hx[m] = (f32x2){0.f, 0.f}; }

    const float* axp = AX + (long)b * 16 + o;
    float ax_cur = axp[0];
    float ax_nxt = axp[B_DIM * 16];
    axp += 2 * B_DIM * 16;

    int vbase = 0;
    for (int tb = 0; tb < T_DIM; tb += 8) {
#pragma unroll
        for (int sl = 0; sl < 8; sl++) {
            const int sw6 = (sl << 4) & 0x40;
            // ---- packed dot over full h (both waves) ----
            f32x2 aA = pk_mul2(hl[0], wh2[0]);
            f32x2 aB = pk_mul2(hl[1], wh2[1]);
            f32x2 aC = pk_mul2(hl[2], wh2[2]);
            f32x2 aD = pk_mul2(hl[3], wh2[3]);
            aA = pk_fma2(hl[4], wh2[4], aA);
            aB = pk_fma2(hl[5], wh2[5], aB);
            aC = pk_fma2(hl[6], wh2[6], aC);
            aD = pk_fma2(hl[7], wh2[7], aD);
            aA = pk_fma2(hx[0], wh2[8],  aA);
            aB = pk_fma2(hx[1], wh2[9],  aB);
            aC = pk_fma2(hx[2], wh2[10], aC);
            aD = pk_fma2(hx[3], wh2[11], aD);
            aA = pk_fma2(hx[4], wh2[12], aA);
            aB = pk_fma2(hx[5], wh2[13], aB);
            aC = pk_fma2(hx[6], wh2[14], aC);
            aD = pk_fma2(hx[7], wh2[15], aD);
            f32x2 sAB = pk_add2(aA, aB);
            f32x2 sCD = pk_add2(aC, aD);
            f32x2 sS  = pk_add2(sAB, sCD);
            float acc = sS.x + sS.y;
            acc = dpp_xadd<0xB1>(acc);
            acc = dpp_xadd<0x4E>(acc);
            float zv = tanhf_fast(acc + ax_cur);

            unsigned zb = __float_as_uint(zv);
            float z[16];
#pragma unroll
            for (int oo = 0; oo < 16; oo++)
                z[oo] = __uint_as_float(__builtin_amdgcn_readlane(zb, oo * 4));

            // ---- gates for this wave's single feature f ----
            {
                float gp_f = bo[0] + z[0]*wo[0][0] + z[1]*wo[0][1] + z[2]*wo[0][2] + z[3]*wo[0][3];
                float gp_i = bo[1] + z[4]*wo[1][0] + z[5]*wo[1][1] + z[6]*wo[1][2] + z[7]*wo[1][3];
                float gp_g = bo[2] + z[8]*wo[2][0] + z[9]*wo[2][1] + z[10]*wo[2][2] + z[11]*wo[2][3];
                float gp_o = bo[3] + z[12]*wo[3][0] + z[13]*wo[3][1] + z[14]*wo[3][2] + z[15]*wo[3][3];
                float fg = sigf(gp_f);
                float ig = sigf(gp_i);
                float gg = tanhf_fast(gp_g);
                float og = sigf(gp_o);
                c = fg * c + ig * gg;
                float hval = og * tanhf_fast(c);
                *(float*)(hhc + vbase + sl * 512 + woffs[sl]) = hval;
            }

            __syncthreads();   // both halves of h(t) now visible

            // ---- read full h(t) for next step's dot ----
            const char* const rp = hhc + vbase + sl * 512 + roffs[sl];
#pragma unroll
            for (int m = 0; m < 4; m++) {
                float4 v4 = *(const float4*)(rp + ((m * 64) ^ sw6));
                hl[m * 2]     = (f32x2){v4.x, v4.y};
                hl[m * 2 + 1] = (f32x2){v4.z, v4.w};
            }
#pragma unroll
            for (int m = 0; m < 4; m++) {
                float4 v4 = *(const float4*)(rp + 256 + ((m * 64) ^ sw6));
                hx[m * 2]     = (f32x2){v4.x, v4.y};
                hx[m * 2 + 1] = (f32x2){v4.z, v4.w};
            }

            // rotate distance-2 AX prefetch AFTER the barrier: a full step
            // (~300+ cyc) before the next barrier's vmcnt drain
            ax_cur = ax_nxt;
            ax_nxt = *axp;
            axp += B_DIM * 16;
        }
        vbase += 8 * 512;
    }

    // ================= fused tag head (split mi range across waves) ========
    const int lr = lane & 15;
    const int lg = lane >> 4;
    const bf16x8* wtv = (const bf16x8*)Wtagp;
    bf16x8 wt[4][2];
#pragma unroll
    for (int kk = 0; kk < 4; kk++)
#pragma unroll
        for (int nt = 0; nt < 2; nt++)
            wt[kk][nt] = wtv[(kk * 2 + nt) * 64 + lane];
    float bt0 = btag[lr], bt1 = btag[16 + lr];

    for (int mi = w * 8; mi < w * 8 + 8; mi++) {
        f32x4 acc0 = (f32x4){0.f, 0.f, 0.f, 0.f};
        f32x4 acc1 = (f32x4){0.f, 0.f, 0.f, 0.f};
        const int arow = mi * 16 + lr;
#pragma unroll
        for (int kk = 0; kk < 4; kk++) {
            float4 lo = *(const float4*)(hhc + hhoff(arow, kk * 128 + lg * 32));
            float4 hi = *(const float4*)(hhc + hhoff(arow, kk * 128 + lg * 32 + 16));
            bf16x8 af;
            af[0] = (short)f2bf(lo.x); af[1] = (short)f2bf(lo.y);
            af[2] = (short)f2bf(lo.z); af[3] = (short)f2bf(lo.w);
            af[4] = (short)f2bf(hi.x); af[5] = (short)f2bf(hi.y);
            af[6] = (short)f2bf(hi.z); af[7] = (short)f2bf(hi.w);
            acc0 = __builtin_amdgcn_mfma_f32_16x16x32_bf16(af, wt[kk][0], acc0, 0, 0, 0);
            acc1 = __builtin_amdgcn_mfma_f32_16x16x32_bf16(af, wt[kk][1], acc1, 0, 0, 0);
        }
        float s0[4], s1[4], mx[4], se[4];
#pragma unroll
        for (int reg = 0; reg < 4; reg++) {
            s0[reg] = acc0[reg] + bt0;
            s1[reg] = acc1[reg] + bt1;
            float m = fmaxf(s0[reg], s1[reg]);
#pragma unroll
            for (int d = 8; d >= 1; d >>= 1) m = fmaxf(m, __shfl_xor(m, d));
            mx[reg] = m;
            float e = __expf(s0[reg] - m) + __expf(s1[reg] - m);
#pragma unroll
            for (int d = 8; d >= 1; d >>= 1) e += __shfl_xor(e, d);
            se[reg] = __logf(e);
        }
#pragma unroll
        for (int reg = 0; reg < 4; reg++) {
            long t = mi * 16 + lg * 4 + reg;
            long base = (t * B_DIM + b) * 32;
            OUT[base + lr]      = s0[reg] - mx[reg] - se[reg];
            OUT[base + 16 + lr] = s1[reg] - mx[reg] - se[reg];
        }
    }
}

// ---------------------------------------------------------------------------
extern "C" void kernel_launch(void* const* d_in, const int* in_sizes, int n_in,
                              void* d_out, int out_size, void* d_ws, size_t ws_size,
                              hipStream_t stream)
{
    const float* X    = (const float*)d_in[0];   // [T,B,F]
    const float* adj  = (const float*)d_in[1];   // [B,B]
    const float* W1   = (const float*)d_in[2];   // [F,H1]
    const float* b1   = (const float*)d_in[3];
    const float* W2   = (const float*)d_in[4];   // [H1,H]
    const float* b2   = (const float*)d_in[5];
    const float* Win  = (const float*)d_in[6];   // [4,F+H,Q]
    const float* b_in = (const float*)d_in[7];   // [4,Q]
    const float* Wout = (const float*)d_in[8];   // [4,Q,H]
    const float* bout = (const float*)d_in[9];   // [4,H]
    const float* Wtag = (const float*)d_in[10];  // [H,TAGS]
    const float* btag = (const float*)d_in[11];
    float* OUT = (float*)d_out;

    float* ws = (float*)d_ws;
    float* NSP  = ws;                    // [T,B,16]  1,048,576 f
    float* adjT = ws + 1048576;          // [B,B]        65,536 f
    float* AX   = ws + 1114112;          // [T,B,16]  1,048,576 f (+over-read slack
                                         //  lands in W1p region, never consumed)
    unsigned short* W1p   = (unsigned short*)(ws + 2162688);   // 32768 bf16
    unsigned short* W2p   = W1p + 32768;                       // 32768 bf16
    unsigned short* Winxp = W2p + 32768;                       //  2048 bf16
    unsigned short* Wtagp = Winxp + 2048;                      //  4096 bf16

    prep_kernel<<<dim3(64), dim3(256), 0, stream>>>(W1, W2, Win, Wtag, W1p, W2p, Winxp, Wtagp);
    mlp_mfma_kernel<<<dim3(TB / 64), dim3(256), 0, stream>>>(X, W1p, b1, W2p, b2, Winxp, NSP);
    transpose_kernel<<<dim3(64), dim3(256), 0, stream>>>(adj, adjT);
    aggx_kernel<<<dim3(256), dim3(256), 0, stream>>>(adjT, NSP, b_in, AX);
    lstm_head_kernel<<<dim3(B_DIM), dim3(128), 0, stream>>>(AX, Win, Wout, bout, Wtagp, btag, OUT);
}

// Round 14
// 136.821 us; speedup vs baseline: 1.5311x; 1.0162x over previous
//
#include <hip/hip_runtime.h>
#include <hip/hip_bf16.h>

// Problem dims (fixed)
#define T_DIM 256
#define B_DIM 256
#define F_DIM 128
#define H1_DIM 256
#define H_DIM 128
#define Q_DIM 4
#define TAGS 32
#define TB (T_DIM * B_DIM)   // 65536 rows

typedef __attribute__((ext_vector_type(8))) short bf16x8;
typedef __attribute__((ext_vector_type(4))) float f32x4;
typedef __attribute__((ext_vector_type(2))) float f32x2;

__device__ __forceinline__ float rcpf(float x) { return __builtin_amdgcn_rcpf(x); }
__device__ __forceinline__ float exp2f_hw(float x) { return __builtin_amdgcn_exp2f(x); }

__device__ __forceinline__ float tanhf_fast(float x) {
    float e = exp2f_hw(2.885390081777927f * x);   // exp(2x)
    return 1.0f - 2.0f * rcpf(e + 1.0f);
}
__device__ __forceinline__ float sigf(float x) {
    return rcpf(1.0f + exp2f_hw(-1.4426950408889634f * x));
}

__device__ __forceinline__ unsigned short f2bf(float f) {
    __hip_bfloat16 h = __float2bfloat16(f);   // RNE
    return *reinterpret_cast<unsigned short*>(&h);
}

// Packed f32 ops (VOP3P): 2 f32 lanes per instruction.
__device__ __forceinline__ f32x2 pk_mul2(f32x2 a, f32x2 b) {
    f32x2 d;
    asm("v_pk_mul_f32 %0, %1, %2" : "=v"(d) : "v"(a), "v"(b));
    return d;
}
__device__ __forceinline__ f32x2 pk_add2(f32x2 a, f32x2 b) {
    f32x2 d;
    asm("v_pk_add_f32 %0, %1, %2" : "=v"(d) : "v"(a), "v"(b));
    return d;
}
__device__ __forceinline__ f32x2 pk_fma2(f32x2 a, f32x2 b, f32x2 c) {
    f32x2 d;
    asm("v_pk_fma_f32 %0, %1, %2, %3" : "=v"(d) : "v"(a), "v"(b), "v"(c));
    return d;
}

// DPP cross-lane add within quad: CTRL=0xB1 -> lane^1, CTRL=0x4E -> lane^2
template<int CTRL>
__device__ __forceinline__ float dpp_xadd(float x) {
    int t = __builtin_amdgcn_update_dpp(0, __float_as_int(x), CTRL, 0xF, 0xF, true);
    return x + __int_as_float(t);
}

// ---------------------------------------------------------------------------
// Kernel 0: weight prep (blocks 0..63) + adj transpose (blocks 64..127),
// merged into one launch to cut a kernel-launch gap.
// ---------------------------------------------------------------------------
__global__ __launch_bounds__(256) void prep_transpose_kernel(
    const float* __restrict__ W1, const float* __restrict__ W2,
    const float* __restrict__ Win, const float* __restrict__ Wtag,
    const float* __restrict__ adj,
    unsigned short* __restrict__ W1p, unsigned short* __restrict__ W2p,
    unsigned short* __restrict__ Winxp, unsigned short* __restrict__ Wtagp,
    float* __restrict__ adjT)
{
    __shared__ float tile[32][33];
    const int tid = threadIdx.x;
    if (blockIdx.x >= 64) {
        // ---- transpose ----
        const int blk = blockIdx.x - 64;
        const int bx = blk & 7, by = blk >> 3;
        const int lx = tid & 31, ly = (tid >> 5) * 4;
#pragma unroll
        for (int r = 0; r < 4; r++)
            tile[ly + r][lx] = adj[(long)(by * 32 + ly + r) * 256 + bx * 32 + lx];
        __syncthreads();
#pragma unroll
        for (int r = 0; r < 4; r++)
            adjT[(long)(bx * 32 + ly + r) * 256 + by * 32 + lx] = tile[lx][ly + r];
        return;
    }
    const int gid0 = blockIdx.x * 256 + tid;
    const int gstride = 64 * 256;
    for (int idx = gid0; idx < 32768; idx += gstride) {
        int e = idx & 7, l = (idx >> 3) & 63, t2 = idx >> 9;
        int nb = t2 & 15, kk = t2 >> 4;
        int k = kk * 32 + (l >> 4) * 8 + e, n = nb * 16 + (l & 15);
        W1p[idx] = f2bf(W1[k * 256 + n]);
    }
    for (int idx = gid0; idx < 32768; idx += gstride) {
        int e = idx & 7, l = (idx >> 3) & 63, t2 = idx >> 9;
        int nb = t2 & 7, kk = t2 >> 3;
        int k = kk * 32 + (l >> 4) * 8 + e, n = nb * 16 + (l & 15);
        W2p[idx] = f2bf(W2[k * 128 + n]);
    }
    for (int idx = gid0; idx < 2048; idx += gstride) {
        int e = idx & 7, l = (idx >> 3) & 63, kk = idx >> 9;
        int k = kk * 32 + (l >> 4) * 8 + e, o = l & 15;
        Winxp[idx] = f2bf(Win[(o >> 2) * 1024 + k * 4 + (o & 3)]);
    }
    for (int idx = gid0; idx < 4096; idx += gstride) {
        int e = idx & 7, l = (idx >> 3) & 63, t2 = idx >> 9;
        int nt = t2 & 1, kk = t2 >> 1;
        int k = kk * 32 + (l >> 4) * 8 + e, n = nt * 16 + (l & 15);
        Wtagp[idx] = f2bf(Wtag[k * 32 + n]);
    }
}

// ---------------------------------------------------------------------------
// Kernel 1: MFMA MLP + fused Win_x projection.  (unchanged)
// ---------------------------------------------------------------------------
__global__ __launch_bounds__(256) void mlp_mfma_kernel(
    const float* __restrict__ X, const unsigned short* __restrict__ W1p,
    const float* __restrict__ b1, const unsigned short* __restrict__ W2p,
    const float* __restrict__ b2, const unsigned short* __restrict__ Winxp,
    float* __restrict__ NSP)
{
    __shared__ __align__(16) unsigned short a1_s[64 * 256];
    __shared__ __align__(16) unsigned short xns_s[64 * 128];

    const int tid = threadIdx.x;
    const int w = tid >> 6;
    const int lane = tid & 63;
    const int lr = lane & 15;
    const int lg = lane >> 4;
    const long rowbase = (long)blockIdx.x * 64;

    char* const a1c = (char*)a1_s;
    char* const xnc = (char*)xns_s;

    {
        const int r = tid >> 2;
        const int qc = tid & 3;
        const float4* xg = (const float4*)(X + (rowbase + r) * 128 + qc * 32);
#pragma unroll
        for (int i = 0; i < 4; i++) {
            float4 lo = xg[i * 2], hi = xg[i * 2 + 1];
            bf16x8 v;
            v[0] = (short)f2bf(lo.x); v[1] = (short)f2bf(lo.y);
            v[2] = (short)f2bf(lo.z); v[3] = (short)f2bf(lo.w);
            v[4] = (short)f2bf(hi.x); v[5] = (short)f2bf(hi.y);
            v[6] = (short)f2bf(hi.z); v[7] = (short)f2bf(hi.w);
            int byte = (r * 256 + qc * 64 + i * 16) ^ ((r & 7) << 4);
            *(bf16x8*)(xnc + byte) = v;
        }
    }
    __syncthreads();

    {
        f32x4 acc[4][4];
#pragma unroll
        for (int mi = 0; mi < 4; mi++)
#pragma unroll
            for (int j = 0; j < 4; j++) acc[mi][j] = (f32x4){0.f, 0.f, 0.f, 0.f};

        const bf16x8* w1v = (const bf16x8*)W1p;
#pragma unroll
        for (int kk = 0; kk < 4; kk++) {
            bf16x8 af[4];
#pragma unroll
            for (int mi = 0; mi < 4; mi++) {
                int row = mi * 16 + lr;
                int byte = (row * 256 + kk * 64 + lg * 16) ^ ((row & 7) << 4);
                af[mi] = *(const bf16x8*)(xnc + byte);
            }
            bf16x8 bfv[4];
#pragma unroll
            for (int j = 0; j < 4; j++)
                bfv[j] = w1v[(kk * 16 + (w * 4 + j)) * 64 + lane];
#pragma unroll
            for (int mi = 0; mi < 4; mi++)
#pragma unroll
                for (int j = 0; j < 4; j++)
                    acc[mi][j] = __builtin_amdgcn_mfma_f32_16x16x32_bf16(
                        af[mi], bfv[j], acc[mi][j], 0, 0, 0);
        }

        float b1v[4];
#pragma unroll
        for (int j = 0; j < 4; j++) b1v[j] = b1[(w * 4 + j) * 16 + lr];
#pragma unroll
        for (int mi = 0; mi < 4; mi++)
#pragma unroll
            for (int j = 0; j < 4; j++)
#pragma unroll
                for (int reg = 0; reg < 4; reg++) {
                    int row = mi * 16 + lg * 4 + reg;
                    int col = (w * 4 + j) * 16 + lr;
                    float v = tanhf_fast(acc[mi][j][reg] + b1v[j]);
                    int byte = (row * 512 + col * 2) ^ ((row & 7) << 4);
                    *(unsigned short*)(a1c + byte) = f2bf(v);
                }
    }
    __syncthreads();

    {
        f32x4 acc[4][2];
#pragma unroll
        for (int mi = 0; mi < 4; mi++)
#pragma unroll
            for (int j = 0; j < 2; j++) acc[mi][j] = (f32x4){0.f, 0.f, 0.f, 0.f};

        const bf16x8* w2v = (const bf16x8*)W2p;
#pragma unroll
        for (int kk = 0; kk < 8; kk++) {
            bf16x8 af[4];
#pragma unroll
            for (int mi = 0; mi < 4; mi++) {
                int row = mi * 16 + lr;
                int byte = (row * 512 + kk * 64 + lg * 16) ^ ((row & 7) << 4);
                af[mi] = *(const bf16x8*)(a1c + byte);
            }
            bf16x8 bfv[2];
#pragma unroll
            for (int j = 0; j < 2; j++)
                bfv[j] = w2v[(kk * 8 + (w * 2 + j)) * 64 + lane];
#pragma unroll
            for (int mi = 0; mi < 4; mi++)
#pragma unroll
                for (int j = 0; j < 2; j++)
                    acc[mi][j] = __builtin_amdgcn_mfma_f32_16x16x32_bf16(
                        af[mi], bfv[j], acc[mi][j], 0, 0, 0);
        }

        float b2v[2];
#pragma unroll
        for (int j = 0; j < 2; j++) b2v[j] = b2[(w * 2 + j) * 16 + lr];
#pragma unroll
        for (int mi = 0; mi < 4; mi++)
#pragma unroll
            for (int j = 0; j < 2; j++)
#pragma unroll
                for (int reg = 0; reg < 4; reg++) {
                    int row = mi * 16 + lg * 4 + reg;
                    int col = (w * 2 + j) * 16 + lr;
                    float v = tanhf_fast(acc[mi][j][reg] + b2v[j]);
                    int byte = (row * 256 + col * 2) ^ ((row & 7) << 4);
                    *(unsigned short*)(xnc + byte) = f2bf(v);
                }
    }
    __syncthreads();

    {
        f32x4 acc = (f32x4){0.f, 0.f, 0.f, 0.f};
        const bf16x8* wxv = (const bf16x8*)Winxp;
#pragma unroll
        for (int kk = 0; kk < 4; kk++) {
            int row = w * 16 + lr;
            int byte = (row * 256 + kk * 64 + lg * 16) ^ ((row & 7) << 4);
            bf16x8 af = *(const bf16x8*)(xnc + byte);
            bf16x8 bfv = wxv[kk * 64 + lane];
            acc = __builtin_amdgcn_mfma_f32_16x16x32_bf16(af, bfv, acc, 0, 0, 0);
        }
#pragma unroll
        for (int reg = 0; reg < 4; reg++) {
            int row = w * 16 + lg * 4 + reg;
            NSP[(rowbase + row) * 16 + lr] = acc[reg];
        }
    }
}

// ---------------------------------------------------------------------------
// Kernel 3: AX[t,i,o] = b_in[o] + sum_j adj[i,j] * NSP[t,j,o]
// ---------------------------------------------------------------------------
__global__ __launch_bounds__(256) void aggx_kernel(
    const float* __restrict__ adjT, const float* __restrict__ NSP,
    const float* __restrict__ b_in, float* __restrict__ AX)
{
    __shared__ float4 nsp_s[256 * 4];
    const int tid = threadIdx.x;
    const int t = blockIdx.x;
    {
        const float4* g = (const float4*)(NSP + (long)t * 4096);
#pragma unroll
        for (int i = 0; i < 4; i++) nsp_s[tid + i * 256] = g[tid + i * 256];
    }
    __syncthreads();

    float4 acc[4];
#pragma unroll
    for (int p = 0; p < 4; p++) acc[p] = ((const float4*)b_in)[p];

    const float* arow = adjT + tid;
    float a[8], an[8];
#pragma unroll
    for (int m = 0; m < 8; m++) an[m] = arow[m * 256];
    for (int j0 = 0; j0 < 256; j0 += 8) {
#pragma unroll
        for (int m = 0; m < 8; m++) a[m] = an[m];
        if (j0 + 8 < 256) {
#pragma unroll
            for (int m = 0; m < 8; m++) an[m] = arow[(j0 + 8 + m) * 256];
        }
#pragma unroll
        for (int m = 0; m < 8; m++) {
            float av = a[m];
#pragma unroll
            for (int p = 0; p < 4; p++) {
                float4 nv = nsp_s[(j0 + m) * 4 + p];
                acc[p].x += av * nv.x; acc[p].y += av * nv.y;
                acc[p].z += av * nv.z; acc[p].w += av * nv.w;
            }
        }
    }
    float4* out = (float4*)(AX + (long)t * 4096 + tid * 16);
#pragma unroll
    for (int p = 0; p < 4; p++) out[p] = acc[p];
}

// ---------------------------------------------------------------------------
// Kernel 4: LSTM scan + FUSED tag head. TWO waves per batch element.
// Round-14: own-half h reads are issued BEFORE the barrier (per-wave DS
// ordering makes them correct; their latency hides under the barrier's
// lgkm drain). Only the other wave's half is read post-barrier -> the
// post-barrier LDS dependency halves, and the own-half partial dot can
// issue while the other-half reads are in flight. Weight halves are
// swapped at init for wave 1 so dot indexing stays compile-time.
// ---------------------------------------------------------------------------
__device__ __forceinline__ int hhoff(int row, int inrow) {
    return (row * 512 + inrow) ^ ((row & 7) << 4);
}

__global__ __attribute__((amdgpu_waves_per_eu(1, 1))) __launch_bounds__(128)
void lstm_head_kernel(
    const float* __restrict__ AX, const float* __restrict__ Win,
    const float* __restrict__ Wout, const float* __restrict__ b_out,
    const unsigned short* __restrict__ Wtagp, const float* __restrict__ btag,
    float* __restrict__ OUT)
{
    __shared__ __align__(16) float hh[T_DIM * 128];   // 128 KB, swizzled rows
    char* const hhc = (char*)hh;

    const int tid = threadIdx.x;
    const int w = tid >> 6;        // wave: h-half owner (features w*64..w*64+63)
    const int lane = tid & 63;
    const int b = blockIdx.x;
    const int o = lane >> 2;
    const int s = lane & 3;
    const int g_o = o >> 2, q_o = o & 3;

    // wh2: [0..7] = k in [0,64) (pairs), [8..15] = k in [64,128)
    f32x2 wh2[16];
#pragma unroll
    for (int m = 0; m < 8; m++)
#pragma unroll
        for (int p = 0; p < 2; p++) {
            int k0 = m * 16 + s * 4 + p * 2;
            f32x2 v;
            v.x = Win[g_o * 1024 + 512 + k0 * 4 + q_o];
            v.y = Win[g_o * 1024 + 512 + (k0 + 1) * 4 + q_o];
            wh2[m * 2 + p] = v;
        }
    // swap halves for wave 1 so wh2[0..7] always multiplies the OWN half
    {
        const bool sw = (w == 1);
#pragma unroll
        for (int i = 0; i < 8; i++) {
            f32x2 a = wh2[i], bv = wh2[i + 8];
            wh2[i]     = sw ? bv : a;
            wh2[i + 8] = sw ? a : bv;
        }
    }

    // gate weights for THIS wave's feature f = w*64 + lane
    const int f = w * 64 + lane;
    float wo[4][4];
    float bo[4];
#pragma unroll
    for (int g = 0; g < 4; g++) {
        bo[g] = b_out[g * 128 + f];
#pragma unroll
        for (int q = 0; q < 4; q++)
            wo[g][q] = Wout[(g * 4 + q) * 128 + f];
    }

    const int own_off = w << 8;          // byte base of own half within a row
    const int oth_off = own_off ^ 256;   // other half
    int woffs[8], roffs[8];
#pragma unroll
    for (int sl = 0; sl < 8; sl++) {
        woffs[sl] = ((lane * 4) ^ (sl << 4)) + own_off;
        roffs[sl] = (s * 16) ^ ((sl << 4) & 0x30);
    }

    float c = 0.f;
    f32x2 hown[8], hoth[8];
#pragma unroll
    for (int m = 0; m < 8; m++) { hown[m] = (f32x2){0.f, 0.f}; hoth[m] = (f32x2){0.f, 0.f}; }

    const float* axp = AX + (long)b * 16 + o;
    float ax_cur = axp[0];
    float ax_nxt = axp[B_DIM * 16];
    axp += 2 * B_DIM * 16;

    int vbase = 0;
    for (int tb = 0; tb < T_DIM; tb += 8) {
#pragma unroll
        for (int sl = 0; sl < 8; sl++) {
            const int sw6 = (sl << 4) & 0x40;
            // ---- packed dot: own half first (regs ready), other half second ----
            f32x2 aA = pk_mul2(hown[0], wh2[0]);
            f32x2 aB = pk_mul2(hown[1], wh2[1]);
            f32x2 aC = pk_mul2(hown[2], wh2[2]);
            f32x2 aD = pk_mul2(hown[3], wh2[3]);
            aA = pk_fma2(hown[4], wh2[4], aA);
            aB = pk_fma2(hown[5], wh2[5], aB);
            aC = pk_fma2(hown[6], wh2[6], aC);
            aD = pk_fma2(hown[7], wh2[7], aD);
            aA = pk_fma2(hoth[0], wh2[8],  aA);
            aB = pk_fma2(hoth[1], wh2[9],  aB);
            aC = pk_fma2(hoth[2], wh2[10], aC);
            aD = pk_fma2(hoth[3], wh2[11], aD);
            aA = pk_fma2(hoth[4], wh2[12], aA);
            aB = pk_fma2(hoth[5], wh2[13], aB);
            aC = pk_fma2(hoth[6], wh2[14], aC);
            aD = pk_fma2(hoth[7], wh2[15], aD);
            f32x2 sAB = pk_add2(aA, aB);
            f32x2 sCD = pk_add2(aC, aD);
            f32x2 sS  = pk_add2(sAB, sCD);
            float acc = sS.x + sS.y;
            acc = dpp_xadd<0xB1>(acc);
            acc = dpp_xadd<0x4E>(acc);
            float zv = tanhf_fast(acc + ax_cur);

            unsigned zb = __float_as_uint(zv);
            float z[16];
#pragma unroll
            for (int oo = 0; oo < 16; oo++)
                z[oo] = __uint_as_float(__builtin_amdgcn_readlane(zb, oo * 4));

            // ---- gates for this wave's single feature f ----
            {
                float gp_f = bo[0] + z[0]*wo[0][0] + z[1]*wo[0][1] + z[2]*wo[0][2] + z[3]*wo[0][3];
                float gp_i = bo[1] + z[4]*wo[1][0] + z[5]*wo[1][1] + z[6]*wo[1][2] + z[7]*wo[1][3];
                float gp_g = bo[2] + z[8]*wo[2][0] + z[9]*wo[2][1] + z[10]*wo[2][2] + z[11]*wo[2][3];
                float gp_o = bo[3] + z[12]*wo[3][0] + z[13]*wo[3][1] + z[14]*wo[3][2] + z[15]*wo[3][3];
                float fg = sigf(gp_f);
                float ig = sigf(gp_i);
                float gg = tanhf_fast(gp_g);
                float og = sigf(gp_o);
                c = fg * c + ig * gg;
                float hval = og * tanhf_fast(c);
                *(float*)(hhc + vbase + sl * 512 + woffs[sl]) = hval;
            }

            // pre-barrier: read back OWN half (in-wave DS ordering makes this
            // correct; latency hides under the barrier's lgkm drain)
            const char* const rp = hhc + vbase + sl * 512 + roffs[sl];
#pragma unroll
            for (int m = 0; m < 4; m++) {
                float4 v4 = *(const float4*)(rp + own_off + ((m * 64) ^ sw6));
                hown[m * 2]     = (f32x2){v4.x, v4.y};
                hown[m * 2 + 1] = (f32x2){v4.z, v4.w};
            }

            __syncthreads();   // other wave's half now visible

            // rotate distance-2 AX prefetch right after the barrier
            ax_cur = ax_nxt;
            ax_nxt = *axp;
            axp += B_DIM * 16;

            // post-barrier: read the OTHER wave's half
#pragma unroll
            for (int m = 0; m < 4; m++) {
                float4 v4 = *(const float4*)(rp + oth_off + ((m * 64) ^ sw6));
                hoth[m * 2]     = (f32x2){v4.x, v4.y};
                hoth[m * 2 + 1] = (f32x2){v4.z, v4.w};
            }
        }
        vbase += 8 * 512;
    }

    // ================= fused tag head (split mi range across waves) ========
    const int lr = lane & 15;
    const int lg = lane >> 4;
    const bf16x8* wtv = (const bf16x8*)Wtagp;
    bf16x8 wt[4][2];
#pragma unroll
    for (int kk = 0; kk < 4; kk++)
#pragma unroll
        for (int nt = 0; nt < 2; nt++)
            wt[kk][nt] = wtv[(kk * 2 + nt) * 64 + lane];
    float bt0 = btag[lr], bt1 = btag[16 + lr];

    for (int mi = w * 8; mi < w * 8 + 8; mi++) {
        f32x4 acc0 = (f32x4){0.f, 0.f, 0.f, 0.f};
        f32x4 acc1 = (f32x4){0.f, 0.f, 0.f, 0.f};
        const int arow = mi * 16 + lr;
#pragma unroll
        for (int kk = 0; kk < 4; kk++) {
            float4 lo = *(const float4*)(hhc + hhoff(arow, kk * 128 + lg * 32));
            float4 hi = *(const float4*)(hhc + hhoff(arow, kk * 128 + lg * 32 + 16));
            bf16x8 af;
            af[0] = (short)f2bf(lo.x); af[1] = (short)f2bf(lo.y);
            af[2] = (short)f2bf(lo.z); af[3] = (short)f2bf(lo.w);
            af[4] = (short)f2bf(hi.x); af[5] = (short)f2bf(hi.y);
            af[6] = (short)f2bf(hi.z); af[7] = (short)f2bf(hi.w);
            acc0 = __builtin_amdgcn_mfma_f32_16x16x32_bf16(af, wt[kk][0], acc0, 0, 0, 0);
            acc1 = __builtin_amdgcn_mfma_f32_16x16x32_bf16(af, wt[kk][1], acc1, 0, 0, 0);
        }
        float s0[4], s1[4], mx[4], se[4];
#pragma unroll
        for (int reg = 0; reg < 4; reg++) {
            s0[reg] = acc0[reg] + bt0;
            s1[reg] = acc1[reg] + bt1;
            float m = fmaxf(s0[reg], s1[reg]);
#pragma unroll
            for (int d = 8; d >= 1; d >>= 1) m = fmaxf(m, __shfl_xor(m, d));
            mx[reg] = m;
            float e = __expf(s0[reg] - m) + __expf(s1[reg] - m);
#pragma unroll
            for (int d = 8; d >= 1; d >>= 1) e += __shfl_xor(e, d);
            se[reg] = __logf(e);
        }
#pragma unroll
        for (int reg = 0; reg < 4; reg++) {
            long t = mi * 16 + lg * 4 + reg;
            long base = (t * B_DIM + b) * 32;
            OUT[base + lr]      = s0[reg] - mx[reg] - se[reg];
            OUT[base + 16 + lr] = s1[reg] - mx[reg] - se[reg];
        }
    }
}

// ---------------------------------------------------------------------------
extern "C" void kernel_launch(void* const* d_in, const int* in_sizes, int n_in,
                              void* d_out, int out_size, void* d_ws, size_t ws_size,
                              hipStream_t stream)
{
    const float* X    = (const float*)d_in[0];   // [T,B,F]
    const float* adj  = (const float*)d_in[1];   // [B,B]
    const float* W1   = (const float*)d_in[2];   // [F,H1]
    const float* b1   = (const float*)d_in[3];
    const float* W2   = (const float*)d_in[4];   // [H1,H]
    const float* b2   = (const float*)d_in[5];
    const float* Win  = (const float*)d_in[6];   // [4,F+H,Q]
    const float* b_in = (const float*)d_in[7];   // [4,Q]
    const float* Wout = (const float*)d_in[8];   // [4,Q,H]
    const float* bout = (const float*)d_in[9];   // [4,H]
    const float* Wtag = (const float*)d_in[10];  // [H,TAGS]
    const float* btag = (const float*)d_in[11];
    float* OUT = (float*)d_out;

    float* ws = (float*)d_ws;
    float* NSP  = ws;                    // [T,B,16]  1,048,576 f
    float* adjT = ws + 1048576;          // [B,B]        65,536 f
    float* AX   = ws + 1114112;          // [T,B,16]  1,048,576 f (+over-read slack
                                         //  lands in W1p region, never consumed)
    unsigned short* W1p   = (unsigned short*)(ws + 2162688);   // 32768 bf16
    unsigned short* W2p   = W1p + 32768;                       // 32768 bf16
    unsigned short* Winxp = W2p + 32768;                       //  2048 bf16
    unsigned short* Wtagp = Winxp + 2048;                      //  4096 bf16

    prep_transpose_kernel<<<dim3(128), dim3(256), 0, stream>>>(
        W1, W2, Win, Wtag, adj, W1p, W2p, Winxp, Wtagp, adjT);
    mlp_mfma_kernel<<<dim3(TB / 64), dim3(256), 0, stream>>>(X, W1p, b1, W2p, b2, Winxp, NSP);
    aggx_kernel<<<dim3(256), dim3(256), 0, stream>>>(adjT, NSP, b_in, AX);
    lstm_head_kernel<<<dim3(B_DIM), dim3(128), 0, stream>>>(AX, Win, Wout, bout, Wtagp, btag, OUT);
}